// Round 7
// baseline (306.137 us; speedup 1.0000x reference)
//
#include <hip/hip_runtime.h>
#include <hip/hip_bf16.h>
#include <math.h>

#define FDIM 128
#define RDIM 20
#define BN   8000
#define NPAIR 512000
#define PB   64
#define ROWS 8

typedef __attribute__((ext_vector_type(8))) short short8v;
typedef __attribute__((ext_vector_type(4))) float float4v;

// fast ShiftedSoftplus: max(x,0) + log(1+exp(-|x|)) - ln2, fast intrinsics
__device__ __forceinline__ float sspf_fast(float x) {
    return fmaxf(x, 0.0f) + __logf(1.0f + __expf(-fabsf(x))) - 0.69314718055994531f;
}
// precise version for the small row-GEMMs (cheap there)
__device__ __forceinline__ float sspf(float x) {
    return fmaxf(x, 0.0f) + log1pf(expf(-fabsf(x))) - 0.69314718055994531f;
}

// HW bf16 converts (v_cvt_pk_bf16_f32), RNE — replaces 4-op software f2bf
__device__ __forceinline__ unsigned short bfs(float a) {
    union { __hip_bfloat16 h; unsigned short u; } v;
    v.h = __float2bfloat16(a);
    return v.u;
}
__device__ __forceinline__ unsigned pkbf(float a, float b) {
    union { __hip_bfloat162 h; unsigned u; } v;
    v.h = __float22bfloat162_rn(make_float2(a, b));
    return v.u;
}

// ---------------------------------------------------------------------------
// CSR preprocessing: histogram -> exclusive scan -> scatter
__global__ __launch_bounds__(256) void hist_kernel(
    const int* __restrict__ idx_i, int* __restrict__ cnt)
{
    const int p = blockIdx.x * 256 + threadIdx.x;
    if (p < NPAIR) atomicAdd(&cnt[idx_i[p]], 1);
}

__global__ __launch_bounds__(1024) void scan_kernel(
    const int* __restrict__ cnt, int* __restrict__ cursor)
{
    __shared__ int part[1024];
    const int t = threadIdx.x;
    int v[8]; int sum = 0;
    #pragma unroll
    for (int k = 0; k < 8; ++k) {
        const int i = t * 8 + k;
        const int c = (i < BN) ? cnt[i] : 0;
        v[k] = sum; sum += c;
    }
    part[t] = sum;
    __syncthreads();
    for (int off = 1; off < 1024; off <<= 1) {
        const int x = (t >= off) ? part[t - off] : 0;
        __syncthreads();
        part[t] += x;
        __syncthreads();
    }
    const int base = (t == 0) ? 0 : part[t - 1];
    #pragma unroll
    for (int k = 0; k < 8; ++k) {
        const int i = t * 8 + k;
        if (i < BN) cursor[i] = base + v[k];
    }
}

// after this kernel cursor[r] = end offset of row r's segment
__global__ __launch_bounds__(256) void scatter_kernel(
    const int* __restrict__ idx_i, int* __restrict__ cursor, int* __restrict__ perm)
{
    const int p = blockIdx.x * 256 + threadIdx.x;
    if (p < NPAIR) {
        const int pos = atomicAdd(&cursor[idx_i[p]], 1);
        perm[pos] = p;
    }
}

// ---------------------------------------------------------------------------
// C[p, :] = act(A[p, :] @ W + bias), 16 rows per block, 256 threads.
template<bool SSP, bool BF16OUT>
__global__ __launch_bounds__(256) void rowgemm_kernel(
    const float* __restrict__ A, const float* __restrict__ W,
    const float* __restrict__ bias, void* __restrict__ Cv)
{
    __shared__ float rowlds[16 * 128];
    const int tid = threadIdx.x;
    const int blk = blockIdx.x;
    for (int s = tid; s < 16 * 128; s += 256)
        rowlds[s] = A[blk * 16 * 128 + s];
    __syncthreads();

    const int lane = tid & 63;
    const int wave = tid >> 6;
    const float b0 = bias[lane];
    const float b1 = bias[64 + lane];
    float acc[4][2];
    #pragma unroll
    for (int rr = 0; rr < 4; ++rr) { acc[rr][0] = b0; acc[rr][1] = b1; }

    #pragma unroll 4
    for (int m = 0; m < 128; ++m) {
        const float w0 = W[m * 128 + lane];
        const float w1 = W[m * 128 + 64 + lane];
        #pragma unroll
        for (int rr = 0; rr < 4; ++rr) {
            const float av = rowlds[(wave * 4 + rr) * 128 + m];
            acc[rr][0] = fmaf(av, w0, acc[rr][0]);
            acc[rr][1] = fmaf(av, w1, acc[rr][1]);
        }
    }

    #pragma unroll
    for (int rr = 0; rr < 4; ++rr) {
        const int p = blk * 16 + wave * 4 + rr;
        float v0 = acc[rr][0], v1 = acc[rr][1];
        if (SSP) { v0 = sspf(v0); v1 = sspf(v1); }
        if (BF16OUT) {
            unsigned short* C = (unsigned short*)Cv;
            C[p * 128 + lane]      = bfs(v0);
            C[p * 128 + 64 + lane] = bfs(v1);
        } else {
            float* C = (float*)Cv;
            C[p * 128 + lane]      = v0;
            C[p * 128 + 64 + lane] = v1;
        }
    }
}

// ---------------------------------------------------------------------------
// Row-centric MFMA pairs kernel over CSR-sorted pairs, register-slimmed for
// 4 waves/EU occupancy. Block b owns rows [b*ROWS, b*ROWS+ROWS). No atomics.
//   L1: act^T = ssp(Wf1^T x f^T + b1)            (f B-frags direct from global)
//   L2 (per mt half): Wij^T = Wf2^T x act^T + b2, then
//   X[p][c] = h[idx_j_p][c] * Wij[p][c] * rcut_p  (bf16, [c][p] in xbuf)
//   AGG: aggT += X^T x S^T (S = row-indicator in regs; D regs accumulate)
__global__ __launch_bounds__(256, 4) void pairs_v7(
    const float* __restrict__ f_ij, const int* __restrict__ idx_i,
    const int* __restrict__ idx_j, const float* __restrict__ rcut,
    const float* __restrict__ Wf1, const float* __restrict__ bf1,
    const float* __restrict__ Wf2, const float* __restrict__ bf2,
    const unsigned short* __restrict__ h2, const int* __restrict__ rowEnd,
    const int* __restrict__ perm, float* __restrict__ agg)
{
    __shared__ unsigned short act[64 * 128];   // [pair][k] bf16, stride 256B, swz ((p&7)<<4)
    __shared__ unsigned short xbuf[128 * 64];  // [c][pair] bf16, stride 128B, swz ((c&7)<<4)
    __shared__ int   rrs[PB];
    __shared__ int   jjs[PB];
    __shared__ float rcs[PB];

    const int tid = threadIdx.x;
    const int w   = tid >> 6;       // wave 0..3: owns cols [w*32, w*32+32)
    const int l   = tid & 63;
    const int l15 = l & 15;
    const int l4  = l >> 4;
    const int swz = (l15 & 7) << 4;

    const int row0 = blockIdx.x * ROWS;
    const int s0 = (row0 == 0) ? 0 : rowEnd[row0 - 1];
    const int s1 = rowEnd[row0 + ROWS - 1];

    // ---- weight fragments in registers ----
    short8v wf1a[2];
    #pragma unroll
    for (int kt2 = 0; kt2 < 2; ++kt2) {
        const int ck = w * 32 + kt2 * 16 + l15;
        #pragma unroll
        for (int e = 0; e < 8; ++e) {
            const int r = l4 * 8 + e;
            const float val = (r < RDIM) ? Wf1[r * 128 + ck] : 0.0f;
            wf1a[kt2][e] = (short)bfs(val);
        }
    }
    short8v wf2a[2][4];
    #pragma unroll
    for (int mt = 0; mt < 2; ++mt) {
        const int c = w * 32 + mt * 16 + l15;
        #pragma unroll
        for (int ks = 0; ks < 4; ++ks) {
            #pragma unroll
            for (int e = 0; e < 8; ++e) {
                const int k = ks * 32 + l4 * 8 + e;
                wf2a[mt][ks][e] = (short)bfs(Wf2[k * 128 + c]);
            }
        }
    }
    float b1v[2][4], b2v[2][4];
    #pragma unroll
    for (int t = 0; t < 2; ++t)
        #pragma unroll
        for (int j = 0; j < 4; ++j) {
            b1v[t][j] = bf1[w * 32 + t * 16 + l4 * 4 + j];
            b2v[t][j] = bf2[w * 32 + t * 16 + l4 * 4 + j];
        }

    // agg accumulator in MFMA D regs: accD[mt] holds aggT[c = w*32+mt*16+l4*4+j][r = l15]
    float4v accD[2];
    accD[0] = float4v{0.f, 0.f, 0.f, 0.f};
    accD[1] = float4v{0.f, 0.f, 0.f, 0.f};

    for (int s = s0; s < s1; s += PB) {
        __syncthreads();   // barA: all waves done with prev chunk's meta/xbuf reads

        // ---- stage pair metadata (LDS, wave0) ----
        if (tid < PB) {
            const int q  = s + tid;
            const int qc = q < s1 ? q : s1 - 1;
            const int pid = perm[qc];
            rrs[tid] = idx_i[pid] - row0;            // in [0,ROWS)
            jjs[tid] = idx_j[pid];
            rcs[tid] = (q < s1) ? rcut[pid] : 0.0f;  // pad slots contribute 0
        }

        // ---- layer-1 B-frags straight from global (k-contiguous per lane) ----
        short8v ffr[4];
        #pragma unroll
        for (int nt = 0; nt < 4; ++nt) {
            const int q = s + nt * 16 + l15;
            const int pid = perm[q < s1 ? q : s1 - 1];
            const float* fb = &f_ij[(size_t)pid * RDIM];
            float4 fa = {0.f, 0.f, 0.f, 0.f}, fc = {0.f, 0.f, 0.f, 0.f};
            if (l4 < 3) fa = *(const float4*)(fb + l4 * 8);       // l4=2 -> k 16..19
            if (l4 < 2) fc = *(const float4*)(fb + l4 * 8 + 4);
            union { unsigned u[4]; short8v v; } pk;
            pk.u[0] = pkbf(fa.x, fa.y); pk.u[1] = pkbf(fa.z, fa.w);
            pk.u[2] = pkbf(fc.x, fc.y); pk.u[3] = pkbf(fc.z, fc.w);
            ffr[nt] = pk.v;
        }
        __syncthreads();   // barB: metadata ready

        // ---- layer 1: act^T = ssp(Wf1^T x f^T + b1) -> act as [pair][k] ----
        #pragma unroll
        for (int kt2 = 0; kt2 < 2; ++kt2) {
            #pragma unroll
            for (int nt = 0; nt < 4; ++nt) {
                float4v acc1 = {0.f, 0.f, 0.f, 0.f};
                acc1 = __builtin_amdgcn_mfma_f32_16x16x32_bf16(wf1a[kt2], ffr[nt], acc1, 0, 0, 0);
                const unsigned lo = pkbf(sspf_fast(acc1[0] + b1v[kt2][0]),
                                         sspf_fast(acc1[1] + b1v[kt2][1]));
                const unsigned hi = pkbf(sspf_fast(acc1[2] + b1v[kt2][2]),
                                         sspf_fast(acc1[3] + b1v[kt2][3]));
                const int row = nt * 16 + l15;
                const int byte = row * 256 + ((w * 64 + kt2 * 32 + l4 * 8) ^ swz);
                *(unsigned long long*)((char*)act + byte) =
                    (unsigned long long)lo | ((unsigned long long)hi << 32);
            }
        }
        __syncthreads();   // barC: act ready (cross-wave)

        // ---- layer 2 + X build, one mt half at a time (register-slim) ----
        #pragma unroll
        for (int mt = 0; mt < 2; ++mt) {
            // h gather for this half (bf16, L2-resident); hidden under the MFMAs
            unsigned long long hv[4];
            #pragma unroll
            for (int nt = 0; nt < 4; ++nt) {
                const int gj = jjs[nt * 16 + l15] << 7;
                hv[nt] = *(const unsigned long long*)&h2[gj + w * 32 + mt * 16 + l4 * 4];
            }

            float4v a2[4];
            #pragma unroll
            for (int nt = 0; nt < 4; ++nt) a2[nt] = float4v{0.f, 0.f, 0.f, 0.f};

            #pragma unroll
            for (int ks = 0; ks < 4; ++ks) {
                short8v bfr[4];
                #pragma unroll
                for (int nt = 0; nt < 4; ++nt) {
                    const int row = nt * 16 + l15;
                    const int byte = row * 256 + ((ks * 64 + l4 * 16) ^ swz);
                    bfr[nt] = *(const short8v*)((const char*)act + byte);
                }
                #pragma unroll
                for (int nt = 0; nt < 4; ++nt)
                    a2[nt] = __builtin_amdgcn_mfma_f32_16x16x32_bf16(
                        wf2a[mt][ks], bfr[nt], a2[nt], 0, 0, 0);
            }

            // X[p][c] = h*(Wij+b2)*rcut -> bf16, stored [c][p] (same-wave rows)
            #pragma unroll
            for (int nt = 0; nt < 4; ++nt) {
                const int p = nt * 16 + l15;
                const float r = rcs[p];
                const unsigned lo = (unsigned)hv[nt];
                const unsigned hi = (unsigned)(hv[nt] >> 32);
                const float hf[4] = {
                    __uint_as_float(lo << 16), __uint_as_float(lo & 0xFFFF0000u),
                    __uint_as_float(hi << 16), __uint_as_float(hi & 0xFFFF0000u) };
                #pragma unroll
                for (int j = 0; j < 4; ++j) {
                    const int c = w * 32 + mt * 16 + l4 * 4 + j;
                    const float xv = hf[j] * ((a2[nt][j] + b2v[mt][j]) * r);
                    const int byte = c * 128 + ((p * 2) ^ ((c & 7) << 4));
                    *(unsigned short*)((char*)xbuf + byte) = bfs(xv);
                }
            }
        }

        // ---- AGG: aggT += X^T x S^T (same-wave rows; no barrier needed) ----
        #pragma unroll
        for (int ks = 0; ks < 2; ++ks) {
            short8v sfr;
            #pragma unroll
            for (int e = 0; e < 8; ++e) {
                const int pr = ks * 32 + l4 * 8 + e;
                sfr[e] = (rrs[pr] == l15) ? (short)0x3F80 : (short)0;  // bf16(1.0)
            }
            #pragma unroll
            for (int mt = 0; mt < 2; ++mt) {
                const int c = w * 32 + mt * 16 + l15;
                const int byte = c * 128 + ((ks * 64 + l4 * 16) ^ swz);
                const short8v xfr = *(const short8v*)((const char*)xbuf + byte);
                accD[mt] = __builtin_amdgcn_mfma_f32_16x16x32_bf16(xfr, sfr, accD[mt], 0, 0, 0);
            }
        }
    }

    // ---- write out: lane holds aggT[c = w*32+mt*16+l4*4+j][r = l15] ----
    if (l15 < ROWS) {
        #pragma unroll
        for (int mt = 0; mt < 2; ++mt) {
            float4 v;
            v.x = accD[mt][0]; v.y = accD[mt][1]; v.z = accD[mt][2]; v.w = accD[mt][3];
            *(float4*)&agg[(size_t)(row0 + l15) * 128 + w * 32 + mt * 16 + l4 * 4] = v;
        }
    }
}

extern "C" void kernel_launch(void* const* d_in, const int* in_sizes, int n_in,
                              void* d_out, int out_size, void* d_ws, size_t ws_size,
                              hipStream_t stream) {
    const float* x     = (const float*)d_in[0];
    const float* f_ij  = (const float*)d_in[1];
    const int*   idx_i = (const int*)  d_in[2];
    const int*   idx_j = (const int*)  d_in[3];
    const float* rcut  = (const float*)d_in[4];
    const float* W_in  = (const float*)d_in[5];
    const float* b_in  = (const float*)d_in[6];
    const float* Wf1   = (const float*)d_in[7];
    const float* bf1   = (const float*)d_in[8];
    const float* Wf2   = (const float*)d_in[9];
    const float* bf2   = (const float*)d_in[10];
    const float* Wo1   = (const float*)d_in[11];
    const float* bo1   = (const float*)d_in[12];
    const float* Wo2   = (const float*)d_in[13];
    const float* bo2   = (const float*)d_in[14];
    float* out = (float*)d_out;

    // ws layout:
    //   h2   : bf16 [8000][128]                        2,048,000 B
    //   agg  : f32  [8000][128]                        4,096,000 B
    //   t1   : f32  [8000][128] (perm/cnt overlay)     4,096,000 B
    unsigned short* h2 = (unsigned short*)d_ws;
    float* agg = (float*)((char*)d_ws + 2048000);
    float* t1  = (float*)((char*)d_ws + 2048000 + 4096000);
    int* perm   = (int*)t1;                               // 512000 ints (t1 overlay)
    int* cnt    = (int*)((char*)t1 + (size_t)NPAIR * 4);  // 8001 ints
    int* cursor = cnt + 8001;                             // 8000 ints

    // CSR sort of pairs by idx_i
    hipMemsetAsync(cnt, 0, (BN + 1) * sizeof(int), stream);
    hist_kernel<<<NPAIR / 256, 256, 0, stream>>>(idx_i, cnt);
    scan_kernel<<<1, 1024, 0, stream>>>(cnt, cursor);
    scatter_kernel<<<NPAIR / 256, 256, 0, stream>>>(idx_i, cursor, perm);

    // h2 = bf16(x @ W_in + b_in)
    rowgemm_kernel<false, true><<<BN / 16, 256, 0, stream>>>(x, W_in, b_in, h2);

    // filter net (MFMA) + gather + MFMA segmented aggregation
    pairs_v7<<<BN / ROWS, 256, 0, stream>>>(
        f_ij, idx_i, idx_j, rcut, Wf1, bf1, Wf2, bf2, h2, cursor, perm, agg);

    // out = ssp(agg @ Wo1 + bo1) @ Wo2 + bo2
    rowgemm_kernel<true,  false><<<BN / 16, 256, 0, stream>>>(agg, Wo1, bo1, t1);
    rowgemm_kernel<false, false><<<BN / 16, 256, 0, stream>>>(t1, Wo2, bo2, out);
}

// Round 8
// 273.110 us; speedup vs baseline: 1.1209x; 1.1209x over previous
//
#include <hip/hip_runtime.h>
#include <hip/hip_bf16.h>
#include <math.h>

#define FDIM 128
#define RDIM 20
#define BN   8000
#define NPAIR 512000
#define PB   64
#define ROWS 8

typedef __attribute__((ext_vector_type(8))) short short8v;
typedef __attribute__((ext_vector_type(4))) float float4v;

// fast ShiftedSoftplus: max(x,0) + log(1+exp(-|x|)) - ln2, fast intrinsics
__device__ __forceinline__ float sspf_fast(float x) {
    return fmaxf(x, 0.0f) + __logf(1.0f + __expf(-fabsf(x))) - 0.69314718055994531f;
}
// precise version for the small row-GEMMs (cheap there)
__device__ __forceinline__ float sspf(float x) {
    return fmaxf(x, 0.0f) + log1pf(expf(-fabsf(x))) - 0.69314718055994531f;
}

// HW bf16 converts (v_cvt_pk_bf16_f32), RNE
__device__ __forceinline__ unsigned short bfs(float a) {
    union { __hip_bfloat16 h; unsigned short u; } v;
    v.h = __float2bfloat16(a);
    return v.u;
}
__device__ __forceinline__ unsigned pkbf(float a, float b) {
    union { __hip_bfloat162 h; unsigned u; } v;
    v.h = __float22bfloat162_rn(make_float2(a, b));
    return v.u;
}

// ---------------------------------------------------------------------------
// CSR preprocessing: histogram -> exclusive scan -> scatter
__global__ __launch_bounds__(256) void hist_kernel(
    const int* __restrict__ idx_i, int* __restrict__ cnt)
{
    const int p = blockIdx.x * 256 + threadIdx.x;
    if (p < NPAIR) atomicAdd(&cnt[idx_i[p]], 1);
}

__global__ __launch_bounds__(1024) void scan_kernel(
    const int* __restrict__ cnt, int* __restrict__ cursor)
{
    __shared__ int part[1024];
    const int t = threadIdx.x;
    int v[8]; int sum = 0;
    #pragma unroll
    for (int k = 0; k < 8; ++k) {
        const int i = t * 8 + k;
        const int c = (i < BN) ? cnt[i] : 0;
        v[k] = sum; sum += c;
    }
    part[t] = sum;
    __syncthreads();
    for (int off = 1; off < 1024; off <<= 1) {
        const int x = (t >= off) ? part[t - off] : 0;
        __syncthreads();
        part[t] += x;
        __syncthreads();
    }
    const int base = (t == 0) ? 0 : part[t - 1];
    #pragma unroll
    for (int k = 0; k < 8; ++k) {
        const int i = t * 8 + k;
        if (i < BN) cursor[i] = base + v[k];
    }
}

// fused path: perm only.   after: cursor[r] = end offset of row r's segment
__global__ __launch_bounds__(256) void scatter_kernel(
    const int* __restrict__ idx_i, int* __restrict__ cursor, int* __restrict__ perm)
{
    const int p = blockIdx.x * 256 + threadIdx.x;
    if (p < NPAIR) {
        const int pos = atomicAdd(&cursor[idx_i[p]], 1);
        perm[pos] = p;
    }
}

// split path: msorted records {pid, idx_j, idx_i&7, 0}
__global__ __launch_bounds__(256) void scatter_split(
    const int* __restrict__ idx_i, const int* __restrict__ idx_j,
    int* __restrict__ cursor, int4* __restrict__ msorted)
{
    const int p = blockIdx.x * 256 + threadIdx.x;
    if (p < NPAIR) {
        const int ii = idx_i[p];
        const int pos = atomicAdd(&cursor[ii], 1);
        msorted[pos] = make_int4(p, idx_j[p], ii & (ROWS - 1), 0);
    }
}

// ---------------------------------------------------------------------------
// C[p, :] = act(A[p, :] @ W + bias), 16 rows per block, 256 threads.
template<bool SSP, bool BF16OUT>
__global__ __launch_bounds__(256) void rowgemm_kernel(
    const float* __restrict__ A, const float* __restrict__ W,
    const float* __restrict__ bias, void* __restrict__ Cv)
{
    __shared__ float rowlds[16 * 128];
    const int tid = threadIdx.x;
    const int blk = blockIdx.x;
    for (int s = tid; s < 16 * 128; s += 256)
        rowlds[s] = A[blk * 16 * 128 + s];
    __syncthreads();

    const int lane = tid & 63;
    const int wave = tid >> 6;
    const float b0 = bias[lane];
    const float b1 = bias[64 + lane];
    float acc[4][2];
    #pragma unroll
    for (int rr = 0; rr < 4; ++rr) { acc[rr][0] = b0; acc[rr][1] = b1; }

    #pragma unroll 4
    for (int m = 0; m < 128; ++m) {
        const float w0 = W[m * 128 + lane];
        const float w1 = W[m * 128 + 64 + lane];
        #pragma unroll
        for (int rr = 0; rr < 4; ++rr) {
            const float av = rowlds[(wave * 4 + rr) * 128 + m];
            acc[rr][0] = fmaf(av, w0, acc[rr][0]);
            acc[rr][1] = fmaf(av, w1, acc[rr][1]);
        }
    }

    #pragma unroll
    for (int rr = 0; rr < 4; ++rr) {
        const int p = blk * 16 + wave * 4 + rr;
        float v0 = acc[rr][0], v1 = acc[rr][1];
        if (SSP) { v0 = sspf(v0); v1 = sspf(v1); }
        if (BF16OUT) {
            unsigned short* C = (unsigned short*)Cv;
            C[p * 128 + lane]      = bfs(v0);
            C[p * 128 + 64 + lane] = bfs(v1);
        } else {
            float* C = (float*)Cv;
            C[p * 128 + lane]      = v0;
            C[p * 128 + 64 + lane] = v1;
        }
    }
}

// ---------------------------------------------------------------------------
// SPLIT kernel A: streaming filter network over UNSORTED pairs.
// Wij[p][c] = (Wf2^T x ssp(Wf1^T x f^T + b1) + b2) * rcut, bf16 out.
__global__ __launch_bounds__(256) void filter_gemm(
    const float* __restrict__ f_ij, const float* __restrict__ rcut,
    const float* __restrict__ Wf1, const float* __restrict__ bf1,
    const float* __restrict__ Wf2, const float* __restrict__ bf2,
    unsigned short* __restrict__ Wij)
{
    __shared__ unsigned short act[64 * 128];   // [pair][k] bf16, stride 256B, swz ((p&7)<<4)
    const int tid = threadIdx.x;
    const int w   = tid >> 6;
    const int l   = tid & 63;
    const int l15 = l & 15;
    const int l4  = l >> 4;
    const int swz = (l15 & 7) << 4;
    const int pbase = blockIdx.x * 64;

    // ---- weight fragments in registers ----
    short8v wf1a[2];
    #pragma unroll
    for (int kt2 = 0; kt2 < 2; ++kt2) {
        const int ck = w * 32 + kt2 * 16 + l15;
        #pragma unroll
        for (int e = 0; e < 8; ++e) {
            const int r = l4 * 8 + e;
            const float val = (r < RDIM) ? Wf1[r * 128 + ck] : 0.0f;
            wf1a[kt2][e] = (short)bfs(val);
        }
    }
    short8v wf2a[2][4];
    #pragma unroll
    for (int mt = 0; mt < 2; ++mt) {
        const int c = w * 32 + mt * 16 + l15;
        #pragma unroll
        for (int ks = 0; ks < 4; ++ks) {
            #pragma unroll
            for (int e = 0; e < 8; ++e) {
                const int k = ks * 32 + l4 * 8 + e;
                wf2a[mt][ks][e] = (short)bfs(Wf2[k * 128 + c]);
            }
        }
    }
    float b1v[2][4], b2v[2][4];
    #pragma unroll
    for (int t = 0; t < 2; ++t)
        #pragma unroll
        for (int j = 0; j < 4; ++j) {
            b1v[t][j] = bf1[w * 32 + t * 16 + l4 * 4 + j];
            b2v[t][j] = bf2[w * 32 + t * 16 + l4 * 4 + j];
        }

    // rcut per output row (D-layout rows)
    float rc[4];
    #pragma unroll
    for (int nt = 0; nt < 4; ++nt)
        rc[nt] = rcut[pbase + nt * 16 + l15];

    // ---- layer-1 B-frags: SEQUENTIAL f_ij reads ----
    short8v ffr[4];
    #pragma unroll
    for (int nt = 0; nt < 4; ++nt) {
        const float* fb = &f_ij[(size_t)(pbase + nt * 16 + l15) * RDIM];
        float4 fa = {0.f, 0.f, 0.f, 0.f}, fc = {0.f, 0.f, 0.f, 0.f};
        if (l4 < 3) fa = *(const float4*)(fb + l4 * 8);       // l4=2 -> k 16..19
        if (l4 < 2) fc = *(const float4*)(fb + l4 * 8 + 4);
        union { unsigned u[4]; short8v v; } pk;
        pk.u[0] = pkbf(fa.x, fa.y); pk.u[1] = pkbf(fa.z, fa.w);
        pk.u[2] = pkbf(fc.x, fc.y); pk.u[3] = pkbf(fc.z, fc.w);
        ffr[nt] = pk.v;
    }

    // ---- layer 1 -> act ----
    #pragma unroll
    for (int kt2 = 0; kt2 < 2; ++kt2) {
        #pragma unroll
        for (int nt = 0; nt < 4; ++nt) {
            float4v acc1 = {0.f, 0.f, 0.f, 0.f};
            acc1 = __builtin_amdgcn_mfma_f32_16x16x32_bf16(wf1a[kt2], ffr[nt], acc1, 0, 0, 0);
            const unsigned lo = pkbf(sspf_fast(acc1[0] + b1v[kt2][0]),
                                     sspf_fast(acc1[1] + b1v[kt2][1]));
            const unsigned hi = pkbf(sspf_fast(acc1[2] + b1v[kt2][2]),
                                     sspf_fast(acc1[3] + b1v[kt2][3]));
            const int row = nt * 16 + l15;
            const int byte = row * 256 + ((w * 64 + kt2 * 32 + l4 * 8) ^ swz);
            *(unsigned long long*)((char*)act + byte) =
                (unsigned long long)lo | ((unsigned long long)hi << 32);
        }
    }
    __syncthreads();   // act ready (cross-wave)

    // ---- layer 2 per mt half; write Wij = (a2+b2)*rcut as bf16 ----
    #pragma unroll
    for (int mt = 0; mt < 2; ++mt) {
        float4v a2[4];
        #pragma unroll
        for (int nt = 0; nt < 4; ++nt) a2[nt] = float4v{0.f, 0.f, 0.f, 0.f};

        #pragma unroll
        for (int ks = 0; ks < 4; ++ks) {
            short8v bfr[4];
            #pragma unroll
            for (int nt = 0; nt < 4; ++nt) {
                const int row = nt * 16 + l15;
                const int byte = row * 256 + ((ks * 64 + l4 * 16) ^ swz);
                bfr[nt] = *(const short8v*)((const char*)act + byte);
            }
            #pragma unroll
            for (int nt = 0; nt < 4; ++nt)
                a2[nt] = __builtin_amdgcn_mfma_f32_16x16x32_bf16(
                    wf2a[mt][ks], bfr[nt], a2[nt], 0, 0, 0);
        }

        #pragma unroll
        for (int nt = 0; nt < 4; ++nt) {
            const size_t p = pbase + nt * 16 + l15;
            uint2 val;
            val.x = pkbf((a2[nt][0] + b2v[mt][0]) * rc[nt],
                         (a2[nt][1] + b2v[mt][1]) * rc[nt]);
            val.y = pkbf((a2[nt][2] + b2v[mt][2]) * rc[nt],
                         (a2[nt][3] + b2v[mt][3]) * rc[nt]);
            *(uint2*)&Wij[p * 128 + w * 32 + mt * 16 + l4 * 4] = val;
        }
    }
}

// ---------------------------------------------------------------------------
// SPLIT kernel B: lightweight sorted aggregation.
// Block b owns rows [b*ROWS, b*ROWS+ROWS). Reads precomputed Wij rows.
__global__ __launch_bounds__(256) void pairs_agg(
    const int4* __restrict__ msorted, const unsigned short* __restrict__ Wij,
    const unsigned short* __restrict__ h2, const int* __restrict__ rowEnd,
    float* __restrict__ agg)
{
    __shared__ unsigned short wlds[64 * 128];  // [p][c] bf16, stride 256B, swz ((p&7)<<4)
    __shared__ unsigned short xbuf[128 * 64];  // [c][p] bf16, stride 128B, swz ((c&7)<<4)
    __shared__ int           jjs[2][PB];
    __shared__ unsigned char rrs[2][PB];

    const int tid = threadIdx.x;
    const int w   = tid >> 6;
    const int l   = tid & 63;
    const int l15 = l & 15;
    const int l4  = l >> 4;
    const int swz = (l15 & 7) << 4;

    const int row0 = blockIdx.x * ROWS;
    const int s0 = (row0 == 0) ? 0 : rowEnd[row0 - 1];
    const int s1 = rowEnd[row0 + ROWS - 1];

    float4v accD[2];
    accD[0] = float4v{0.f, 0.f, 0.f, 0.f};
    accD[1] = float4v{0.f, 0.f, 0.f, 0.f};

    int tb = 0;
    for (int s = s0; s < s1; s += PB, tb ^= 1) {
        // ---- stage metadata ----
        if (tid < PB) {
            const int q  = s + tid;
            const int qc = q < s1 ? q : s1 - 1;
            const int4 m = msorted[qc];
            jjs[tb][tid] = m.y;
            rrs[tb][tid] = (q < s1) ? (unsigned char)m.z : (unsigned char)255;
        }
        // ---- stage Wij chunk: 4 threads per pair, 64B each ----
        {
            const int p4 = tid >> 2, q4 = tid & 3;
            const int q  = s + p4;
            const int qc = q < s1 ? q : s1 - 1;
            const int pid = msorted[qc].x;
            const char* src = (const char*)(Wij + (size_t)pid * 128) + q4 * 64;
            #pragma unroll
            for (int i = 0; i < 4; ++i) {
                const uint4 v = *(const uint4*)(src + i * 16);
                const int byte = p4 * 256 + ((q4 * 64 + i * 16) ^ ((p4 & 7) << 4));
                *(uint4*)((char*)wlds + byte) = v;
            }
        }
        __syncthreads();   // bar1: wlds + meta ready

        // ---- X build: X[p][c] = h2[jj][c] * Wij[p][c] -> bf16 [c][p] ----
        #pragma unroll
        for (int nt = 0; nt < 4; ++nt) {
            const int p   = nt * 16 + l15;
            const int jj  = jjs[tb][p] << 7;
            const int psw = (p & 7) << 4;
            #pragma unroll
            for (int mt = 0; mt < 2; ++mt) {
                const int c0 = w * 32 + mt * 16 + l4 * 4;
                const unsigned long long wv = *(const unsigned long long*)
                    ((const char*)wlds + p * 256 + ((c0 * 2) ^ psw));
                const unsigned long long hv = *(const unsigned long long*)&h2[jj + c0];
                #pragma unroll
                for (int j = 0; j < 4; ++j) {
                    const float wf = __uint_as_float((unsigned)((wv >> (16 * j)) & 0xFFFFULL) << 16);
                    const float hf = __uint_as_float((unsigned)((hv >> (16 * j)) & 0xFFFFULL) << 16);
                    const int c = c0 + j;
                    const int byte = c * 128 + ((p * 2) ^ ((c & 7) << 4));
                    *(unsigned short*)((char*)xbuf + byte) = bfs(hf * wf);
                }
            }
        }
        __syncthreads();   // bar2: xbuf ready

        // ---- AGG: aggT += X^T x S^T ----
        #pragma unroll
        for (int ks = 0; ks < 2; ++ks) {
            short8v sfr;
            #pragma unroll
            for (int e = 0; e < 8; ++e) {
                const int pr = ks * 32 + l4 * 8 + e;
                sfr[e] = (rrs[tb][pr] == (unsigned char)l15) ? (short)0x3F80 : (short)0;
            }
            #pragma unroll
            for (int mt = 0; mt < 2; ++mt) {
                const int c = w * 32 + mt * 16 + l15;
                const int byte = c * 128 + ((ks * 64 + l4 * 16) ^ swz);
                const short8v xfr = *(const short8v*)((const char*)xbuf + byte);
                accD[mt] = __builtin_amdgcn_mfma_f32_16x16x32_bf16(xfr, sfr, accD[mt], 0, 0, 0);
            }
        }
    }

    if (l15 < ROWS) {
        #pragma unroll
        for (int mt = 0; mt < 2; ++mt) {
            float4 v;
            v.x = accD[mt][0]; v.y = accD[mt][1]; v.z = accD[mt][2]; v.w = accD[mt][3];
            *(float4*)&agg[(size_t)(row0 + l15) * 128 + w * 32 + mt * 16 + l4 * 4] = v;
        }
    }
}

// ---------------------------------------------------------------------------
// FUSED fallback (round-6 kernel, used when ws_size is too small for split).
__global__ __launch_bounds__(256) void pairs_mfma_agg(
    const float* __restrict__ f_ij, const int* __restrict__ idx_i,
    const int* __restrict__ idx_j, const float* __restrict__ rcut,
    const float* __restrict__ Wf1, const float* __restrict__ bf1,
    const float* __restrict__ Wf2, const float* __restrict__ bf2,
    const unsigned short* __restrict__ h2, const int* __restrict__ rowEnd,
    const int* __restrict__ perm, float* __restrict__ agg)
{
    __shared__ unsigned short xt[64 * 128];
    __shared__ int   rrs[PB];
    __shared__ int   jjs[PB];
    __shared__ float rcs[PB];

    const int tid = threadIdx.x;
    const int w   = tid >> 6;
    const int l   = tid & 63;
    const int l15 = l & 15;
    const int l4  = l >> 4;
    const int swz = (l15 & 7) << 4;

    const int row0 = blockIdx.x * ROWS;
    const int s0 = (row0 == 0) ? 0 : rowEnd[row0 - 1];
    const int s1 = rowEnd[row0 + ROWS - 1];

    short8v wf1a[2];
    #pragma unroll
    for (int kt2 = 0; kt2 < 2; ++kt2) {
        const int ck = w * 32 + kt2 * 16 + l15;
        #pragma unroll
        for (int e = 0; e < 8; ++e) {
            const int r = l4 * 8 + e;
            const float val = (r < RDIM) ? Wf1[r * 128 + ck] : 0.0f;
            wf1a[kt2][e] = (short)bfs(val);
        }
    }
    short8v wf2a[2][4];
    #pragma unroll
    for (int mt = 0; mt < 2; ++mt) {
        const int c = w * 32 + mt * 16 + l15;
        #pragma unroll
        for (int ks = 0; ks < 4; ++ks) {
            #pragma unroll
            for (int e = 0; e < 8; ++e) {
                const int k = ks * 32 + l4 * 8 + e;
                wf2a[mt][ks][e] = (short)bfs(Wf2[k * 128 + c]);
            }
        }
    }
    float b1v[2][4], b2v[2][4];
    #pragma unroll
    for (int t = 0; t < 2; ++t)
        #pragma unroll
        for (int j = 0; j < 4; ++j) {
            b1v[t][j] = bf1[w * 32 + t * 16 + l4 * 4 + j];
            b2v[t][j] = bf2[w * 32 + t * 16 + l4 * 4 + j];
        }

    float4v accD[2];
    accD[0] = float4v{0.f, 0.f, 0.f, 0.f};
    accD[1] = float4v{0.f, 0.f, 0.f, 0.f};

    for (int s = s0; s < s1; s += PB) {
        __syncthreads();

        if (tid < PB) {
            const int q  = s + tid;
            const int qc = q < s1 ? q : s1 - 1;
            const int pid = perm[qc];
            rrs[tid] = idx_i[pid] - row0;
            jjs[tid] = idx_j[pid];
            rcs[tid] = (q < s1) ? rcut[pid] : 0.0f;
        }

        short8v ffr[4];
        #pragma unroll
        for (int nt = 0; nt < 4; ++nt) {
            const int q = s + nt * 16 + l15;
            const int pid = perm[q < s1 ? q : s1 - 1];
            const float* fb = &f_ij[(size_t)pid * RDIM];
            float4 fa = {0.f, 0.f, 0.f, 0.f}, fc = {0.f, 0.f, 0.f, 0.f};
            if (l4 < 3) fa = *(const float4*)(fb + l4 * 8);
            if (l4 < 2) fc = *(const float4*)(fb + l4 * 8 + 4);
            union { unsigned u[4]; short8v v; } pk;
            pk.u[0] = pkbf(fa.x, fa.y); pk.u[1] = pkbf(fa.z, fa.w);
            pk.u[2] = pkbf(fc.x, fc.y); pk.u[3] = pkbf(fc.z, fc.w);
            ffr[nt] = pk.v;
        }
        __syncthreads();

        unsigned long long hvb[4][2];
        #pragma unroll
        for (int nt = 0; nt < 4; ++nt) {
            const int gj = jjs[nt * 16 + l15] << 7;
            hvb[nt][0] = *(const unsigned long long*)&h2[gj + w * 32 + l4 * 4];
            hvb[nt][1] = *(const unsigned long long*)&h2[gj + w * 32 + 16 + l4 * 4];
        }

        #pragma unroll
        for (int kt2 = 0; kt2 < 2; ++kt2) {
            #pragma unroll
            for (int nt = 0; nt < 4; ++nt) {
                float4v acc1 = {0.f, 0.f, 0.f, 0.f};
                acc1 = __builtin_amdgcn_mfma_f32_16x16x32_bf16(wf1a[kt2], ffr[nt], acc1, 0, 0, 0);
                const unsigned lo = pkbf(sspf_fast(acc1[0] + b1v[kt2][0]),
                                         sspf_fast(acc1[1] + b1v[kt2][1]));
                const unsigned hi = pkbf(sspf_fast(acc1[2] + b1v[kt2][2]),
                                         sspf_fast(acc1[3] + b1v[kt2][3]));
                const int row = nt * 16 + l15;
                const int byte = row * 256 + ((w * 64 + kt2 * 32 + l4 * 8) ^ swz);
                *(unsigned long long*)((char*)xt + byte) =
                    (unsigned long long)lo | ((unsigned long long)hi << 32);
            }
        }
        __syncthreads();

        float4v a2[2][4];
        #pragma unroll
        for (int mt = 0; mt < 2; ++mt)
            #pragma unroll
            for (int nt = 0; nt < 4; ++nt)
                a2[mt][nt] = float4v{0.f, 0.f, 0.f, 0.f};

        #pragma unroll
        for (int ks = 0; ks < 4; ++ks) {
            short8v bfr[4];
            #pragma unroll
            for (int nt = 0; nt < 4; ++nt) {
                const int row = nt * 16 + l15;
                const int byte = row * 256 + ((ks * 64 + l4 * 16) ^ swz);
                bfr[nt] = *(const short8v*)((const char*)xt + byte);
            }
            #pragma unroll
            for (int mt = 0; mt < 2; ++mt)
                #pragma unroll
                for (int nt = 0; nt < 4; ++nt)
                    a2[mt][nt] = __builtin_amdgcn_mfma_f32_16x16x32_bf16(
                        wf2a[mt][ks], bfr[nt], a2[mt][nt], 0, 0, 0);
        }
        __syncthreads();

        #pragma unroll
        for (int nt = 0; nt < 4; ++nt) {
            const int p = nt * 16 + l15;
            const float r = rcs[p];
            #pragma unroll
            for (int mt = 0; mt < 2; ++mt) {
                #pragma unroll
                for (int j = 0; j < 4; ++j) {
                    const int c = w * 32 + mt * 16 + l4 * 4 + j;
                    const float hf = __uint_as_float(
                        (unsigned)((hvb[nt][mt] >> (16 * j)) & 0xFFFFULL) << 16);
                    const float xv = hf * ((a2[mt][nt][j] + b2v[mt][j]) * r);
                    const int byte = c * 128 + ((p * 2) ^ ((c & 7) << 4));
                    *(unsigned short*)((char*)xt + byte) = bfs(xv);
                }
            }
        }
        __syncthreads();

        #pragma unroll
        for (int ks = 0; ks < 2; ++ks) {
            short8v sfr;
            #pragma unroll
            for (int e = 0; e < 8; ++e) {
                const int pr = ks * 32 + l4 * 8 + e;
                sfr[e] = (rrs[pr] == l15) ? (short)0x3F80 : (short)0;
            }
            #pragma unroll
            for (int mt = 0; mt < 2; ++mt) {
                const int c = w * 32 + mt * 16 + l15;
                const int byte = c * 128 + ((ks * 64 + l4 * 16) ^ swz);
                const short8v xfr = *(const short8v*)((const char*)xt + byte);
                accD[mt] = __builtin_amdgcn_mfma_f32_16x16x32_bf16(xfr, sfr, accD[mt], 0, 0, 0);
            }
        }
    }

    if (l15 < ROWS) {
        #pragma unroll
        for (int mt = 0; mt < 2; ++mt) {
            float4 v;
            v.x = accD[mt][0]; v.y = accD[mt][1]; v.z = accD[mt][2]; v.w = accD[mt][3];
            *(float4*)&agg[(size_t)(row0 + l15) * 128 + w * 32 + mt * 16 + l4 * 4] = v;
        }
    }
}

extern "C" void kernel_launch(void* const* d_in, const int* in_sizes, int n_in,
                              void* d_out, int out_size, void* d_ws, size_t ws_size,
                              hipStream_t stream) {
    const float* x     = (const float*)d_in[0];
    const float* f_ij  = (const float*)d_in[1];
    const int*   idx_i = (const int*)  d_in[2];
    const int*   idx_j = (const int*)  d_in[3];
    const float* rcut  = (const float*)d_in[4];
    const float* W_in  = (const float*)d_in[5];
    const float* b_in  = (const float*)d_in[6];
    const float* Wf1   = (const float*)d_in[7];
    const float* bf1   = (const float*)d_in[8];
    const float* Wf2   = (const float*)d_in[9];
    const float* bf2   = (const float*)d_in[10];
    const float* Wo1   = (const float*)d_in[11];
    const float* bo1   = (const float*)d_in[12];
    const float* Wo2   = (const float*)d_in[13];
    const float* bo2   = (const float*)d_in[14];
    float* out = (float*)d_out;

    // common ws layout:
    //   h2      : bf16 [8000][128]                      2,048,000 B
    //   agg     : f32  [8000][128]                      4,096,000 B
    //   t1      : f32  [8000][128] (perm/cnt overlay)   4,096,000 B
    // split-only extra:
    //   msorted : int4 [512000]                         8,192,000 B
    //   Wij     : bf16 [512000][128]                  131,072,000 B
    unsigned short* h2 = (unsigned short*)d_ws;
    float* agg = (float*)((char*)d_ws + 2048000);
    float* t1  = (float*)((char*)d_ws + 2048000 + 4096000);
    int* perm   = (int*)t1;
    int* cnt    = (int*)((char*)t1 + (size_t)NPAIR * 4);
    int* cursor = cnt + 8001;
    int4* msorted      = (int4*)((char*)d_ws + 10240000);
    unsigned short* Wij = (unsigned short*)((char*)d_ws + 10240000 + 8192000);
    const size_t SPLIT_BYTES = 10240000ull + 8192000ull + 131072000ull;

    const bool use_split = (ws_size >= SPLIT_BYTES);

    // CSR sort of pairs by idx_i
    hipMemsetAsync(cnt, 0, (BN + 1) * sizeof(int), stream);
    hist_kernel<<<NPAIR / 256, 256, 0, stream>>>(idx_i, cnt);
    scan_kernel<<<1, 1024, 0, stream>>>(cnt, cursor);
    if (use_split) {
        scatter_split<<<NPAIR / 256, 256, 0, stream>>>(idx_i, idx_j, cursor, msorted);
    } else {
        scatter_kernel<<<NPAIR / 256, 256, 0, stream>>>(idx_i, cursor, perm);
    }

    // h2 = bf16(x @ W_in + b_in)
    rowgemm_kernel<false, true><<<BN / 16, 256, 0, stream>>>(x, W_in, b_in, h2);

    if (use_split) {
        filter_gemm<<<NPAIR / 64, 256, 0, stream>>>(
            f_ij, rcut, Wf1, bf1, Wf2, bf2, Wij);
        pairs_agg<<<BN / ROWS, 256, 0, stream>>>(
            msorted, Wij, h2, cursor, agg);
    } else {
        pairs_mfma_agg<<<BN / ROWS, 256, 0, stream>>>(
            f_ij, idx_i, idx_j, rcut, Wf1, bf1, Wf2, bf2, h2, cursor, perm, agg);
    }

    // out = ssp(agg @ Wo1 + bo1) @ Wo2 + bo2
    rowgemm_kernel<true,  false><<<BN / 16, 256, 0, stream>>>(agg, Wo1, bo1, t1);
    rowgemm_kernel<false, false><<<BN / 16, 256, 0, stream>>>(t1, Wo2, bo2, out);
}

// Round 9
// 243.558 us; speedup vs baseline: 1.2569x; 1.1213x over previous
//
#include <hip/hip_runtime.h>
#include <hip/hip_bf16.h>
#include <math.h>

#define FDIM 128
#define RDIM 20
#define BN   8000
#define NPAIR 512000
#define PB   64
#define ROWS 8
#define NCHUNK (NPAIR / PB)
#define NBLK_FILTER 1280

typedef __attribute__((ext_vector_type(8))) short short8v;
typedef __attribute__((ext_vector_type(4))) float float4v;

// fast ShiftedSoftplus: max(x,0) + log(1+exp(-|x|)) - ln2, fast intrinsics
__device__ __forceinline__ float sspf_fast(float x) {
    return fmaxf(x, 0.0f) + __logf(1.0f + __expf(-fabsf(x))) - 0.69314718055994531f;
}
// precise version for the small row-GEMMs (cheap there)
__device__ __forceinline__ float sspf(float x) {
    return fmaxf(x, 0.0f) + log1pf(expf(-fabsf(x))) - 0.69314718055994531f;
}

// HW bf16 converts (v_cvt_pk_bf16_f32), RNE
__device__ __forceinline__ unsigned short bfs(float a) {
    union { __hip_bfloat16 h; unsigned short u; } v;
    v.h = __float2bfloat16(a);
    return v.u;
}
__device__ __forceinline__ unsigned pkbf(float a, float b) {
    union { __hip_bfloat162 h; unsigned u; } v;
    v.h = __float22bfloat162_rn(make_float2(a, b));
    return v.u;
}

// ---------------------------------------------------------------------------
// CSR preprocessing: histogram -> exclusive scan -> scatter
__global__ __launch_bounds__(256) void hist_kernel(
    const int* __restrict__ idx_i, int* __restrict__ cnt)
{
    const int p = blockIdx.x * 256 + threadIdx.x;
    if (p < NPAIR) atomicAdd(&cnt[idx_i[p]], 1);
}

__global__ __launch_bounds__(1024) void scan_kernel(
    const int* __restrict__ cnt, int* __restrict__ cursor)
{
    __shared__ int part[1024];
    const int t = threadIdx.x;
    int v[8]; int sum = 0;
    #pragma unroll
    for (int k = 0; k < 8; ++k) {
        const int i = t * 8 + k;
        const int c = (i < BN) ? cnt[i] : 0;
        v[k] = sum; sum += c;
    }
    part[t] = sum;
    __syncthreads();
    for (int off = 1; off < 1024; off <<= 1) {
        const int x = (t >= off) ? part[t - off] : 0;
        __syncthreads();
        part[t] += x;
        __syncthreads();
    }
    const int base = (t == 0) ? 0 : part[t - 1];
    #pragma unroll
    for (int k = 0; k < 8; ++k) {
        const int i = t * 8 + k;
        if (i < BN) cursor[i] = base + v[k];
    }
}

// fused path: perm only.   after: cursor[r] = end offset of row r's segment
__global__ __launch_bounds__(256) void scatter_kernel(
    const int* __restrict__ idx_i, int* __restrict__ cursor, int* __restrict__ perm)
{
    const int p = blockIdx.x * 256 + threadIdx.x;
    if (p < NPAIR) {
        const int pos = atomicAdd(&cursor[idx_i[p]], 1);
        perm[pos] = p;
    }
}

// split path: msorted records {pid, idx_j, idx_i&7, 0}
__global__ __launch_bounds__(256) void scatter_split(
    const int* __restrict__ idx_i, const int* __restrict__ idx_j,
    int* __restrict__ cursor, int4* __restrict__ msorted)
{
    const int p = blockIdx.x * 256 + threadIdx.x;
    if (p < NPAIR) {
        const int ii = idx_i[p];
        const int pos = atomicAdd(&cursor[ii], 1);
        msorted[pos] = make_int4(p, idx_j[p], ii & (ROWS - 1), 0);
    }
}

// ---------------------------------------------------------------------------
// C[p, :] = act(A[p, :] @ W + bias), 16 rows per block, 256 threads.
template<bool SSP, bool BF16OUT>
__global__ __launch_bounds__(256) void rowgemm_kernel(
    const float* __restrict__ A, const float* __restrict__ W,
    const float* __restrict__ bias, void* __restrict__ Cv)
{
    __shared__ float rowlds[16 * 128];
    const int tid = threadIdx.x;
    const int blk = blockIdx.x;
    for (int s = tid; s < 16 * 128; s += 256)
        rowlds[s] = A[blk * 16 * 128 + s];
    __syncthreads();

    const int lane = tid & 63;
    const int wave = tid >> 6;
    const float b0 = bias[lane];
    const float b1 = bias[64 + lane];
    float acc[4][2];
    #pragma unroll
    for (int rr = 0; rr < 4; ++rr) { acc[rr][0] = b0; acc[rr][1] = b1; }

    #pragma unroll 4
    for (int m = 0; m < 128; ++m) {
        const float w0 = W[m * 128 + lane];
        const float w1 = W[m * 128 + 64 + lane];
        #pragma unroll
        for (int rr = 0; rr < 4; ++rr) {
            const float av = rowlds[(wave * 4 + rr) * 128 + m];
            acc[rr][0] = fmaf(av, w0, acc[rr][0]);
            acc[rr][1] = fmaf(av, w1, acc[rr][1]);
        }
    }

    #pragma unroll
    for (int rr = 0; rr < 4; ++rr) {
        const int p = blk * 16 + wave * 4 + rr;
        float v0 = acc[rr][0], v1 = acc[rr][1];
        if (SSP) { v0 = sspf(v0); v1 = sspf(v1); }
        if (BF16OUT) {
            unsigned short* C = (unsigned short*)Cv;
            C[p * 128 + lane]      = bfs(v0);
            C[p * 128 + 64 + lane] = bfs(v1);
        } else {
            float* C = (float*)Cv;
            C[p * 128 + lane]      = v0;
            C[p * 128 + 64 + lane] = v1;
        }
    }
}

// ---------------------------------------------------------------------------
// SPLIT kernel A: streaming filter network over UNSORTED pairs, PERSISTENT.
// Weight fragments loaded once per block, amortized over ~NCHUNK/grid chunks.
// Wij[p][c] = (Wf2^T x ssp(Wf1^T x f^T + b1) + b2) * rcut, bf16 out.
__global__ __launch_bounds__(256) void filter_gemm(
    const float* __restrict__ f_ij, const float* __restrict__ rcut,
    const float* __restrict__ Wf1, const float* __restrict__ bf1,
    const float* __restrict__ Wf2, const float* __restrict__ bf2,
    unsigned short* __restrict__ Wij)
{
    __shared__ unsigned short act[64 * 128];   // [pair][k] bf16, stride 256B, swz ((p&7)<<4)
    const int tid = threadIdx.x;
    const int w   = tid >> 6;
    const int l   = tid & 63;
    const int l15 = l & 15;
    const int l4  = l >> 4;
    const int swz = (l15 & 7) << 4;

    // ---- weight fragments in registers (once per block) ----
    short8v wf1a[2];
    #pragma unroll
    for (int kt2 = 0; kt2 < 2; ++kt2) {
        const int ck = w * 32 + kt2 * 16 + l15;
        #pragma unroll
        for (int e = 0; e < 8; ++e) {
            const int r = l4 * 8 + e;
            const float val = (r < RDIM) ? Wf1[r * 128 + ck] : 0.0f;
            wf1a[kt2][e] = (short)bfs(val);
        }
    }
    short8v wf2a[2][4];
    #pragma unroll
    for (int mt = 0; mt < 2; ++mt) {
        const int c = w * 32 + mt * 16 + l15;
        #pragma unroll
        for (int ks = 0; ks < 4; ++ks) {
            #pragma unroll
            for (int e = 0; e < 8; ++e) {
                const int k = ks * 32 + l4 * 8 + e;
                wf2a[mt][ks][e] = (short)bfs(Wf2[k * 128 + c]);
            }
        }
    }
    float b1v[2][4], b2v[2][4];
    #pragma unroll
    for (int t = 0; t < 2; ++t)
        #pragma unroll
        for (int j = 0; j < 4; ++j) {
            b1v[t][j] = bf1[w * 32 + t * 16 + l4 * 4 + j];
            b2v[t][j] = bf2[w * 32 + t * 16 + l4 * 4 + j];
        }

    for (int chunk = blockIdx.x; chunk < NCHUNK; chunk += NBLK_FILTER) {
        const int pbase = chunk * PB;

        // rcut per output row (D-layout rows)
        float rc[4];
        #pragma unroll
        for (int nt = 0; nt < 4; ++nt)
            rc[nt] = rcut[pbase + nt * 16 + l15];

        // ---- layer-1 B-frags: SEQUENTIAL f_ij reads ----
        short8v ffr[4];
        #pragma unroll
        for (int nt = 0; nt < 4; ++nt) {
            const float* fb = &f_ij[(size_t)(pbase + nt * 16 + l15) * RDIM];
            float4 fa = {0.f, 0.f, 0.f, 0.f}, fc = {0.f, 0.f, 0.f, 0.f};
            if (l4 < 3) fa = *(const float4*)(fb + l4 * 8);       // l4=2 -> k 16..19
            if (l4 < 2) fc = *(const float4*)(fb + l4 * 8 + 4);
            union { unsigned u[4]; short8v v; } pk;
            pk.u[0] = pkbf(fa.x, fa.y); pk.u[1] = pkbf(fa.z, fa.w);
            pk.u[2] = pkbf(fc.x, fc.y); pk.u[3] = pkbf(fc.z, fc.w);
            ffr[nt] = pk.v;
        }

        __syncthreads();   // prev chunk's L2 phase fully consumed act

        // ---- layer 1 -> act ----
        #pragma unroll
        for (int kt2 = 0; kt2 < 2; ++kt2) {
            #pragma unroll
            for (int nt = 0; nt < 4; ++nt) {
                float4v acc1 = {0.f, 0.f, 0.f, 0.f};
                acc1 = __builtin_amdgcn_mfma_f32_16x16x32_bf16(wf1a[kt2], ffr[nt], acc1, 0, 0, 0);
                const unsigned lo = pkbf(sspf_fast(acc1[0] + b1v[kt2][0]),
                                         sspf_fast(acc1[1] + b1v[kt2][1]));
                const unsigned hi = pkbf(sspf_fast(acc1[2] + b1v[kt2][2]),
                                         sspf_fast(acc1[3] + b1v[kt2][3]));
                const int row = nt * 16 + l15;
                const int byte = row * 256 + ((w * 64 + kt2 * 32 + l4 * 8) ^ swz);
                *(unsigned long long*)((char*)act + byte) =
                    (unsigned long long)lo | ((unsigned long long)hi << 32);
            }
        }
        __syncthreads();   // act ready (cross-wave)

        // ---- layer 2 per mt half; write Wij = (a2+b2)*rcut as bf16 ----
        #pragma unroll
        for (int mt = 0; mt < 2; ++mt) {
            float4v a2[4];
            #pragma unroll
            for (int nt = 0; nt < 4; ++nt) a2[nt] = float4v{0.f, 0.f, 0.f, 0.f};

            #pragma unroll
            for (int ks = 0; ks < 4; ++ks) {
                short8v bfr[4];
                #pragma unroll
                for (int nt = 0; nt < 4; ++nt) {
                    const int row = nt * 16 + l15;
                    const int byte = row * 256 + ((ks * 64 + l4 * 16) ^ swz);
                    bfr[nt] = *(const short8v*)((const char*)act + byte);
                }
                #pragma unroll
                for (int nt = 0; nt < 4; ++nt)
                    a2[nt] = __builtin_amdgcn_mfma_f32_16x16x32_bf16(
                        wf2a[mt][ks], bfr[nt], a2[nt], 0, 0, 0);
            }

            #pragma unroll
            for (int nt = 0; nt < 4; ++nt) {
                const size_t p = pbase + nt * 16 + l15;
                uint2 val;
                val.x = pkbf((a2[nt][0] + b2v[mt][0]) * rc[nt],
                             (a2[nt][1] + b2v[mt][1]) * rc[nt]);
                val.y = pkbf((a2[nt][2] + b2v[mt][2]) * rc[nt],
                             (a2[nt][3] + b2v[mt][3]) * rc[nt]);
                *(uint2*)&Wij[p * 128 + w * 32 + mt * 16 + l4 * 4] = val;
            }
        }
    }
}

// ---------------------------------------------------------------------------
// SPLIT kernel B: lightweight sorted aggregation.
// Block b owns rows [b*ROWS, b*ROWS+ROWS). Reads precomputed Wij rows.
__global__ __launch_bounds__(256) void pairs_agg(
    const int4* __restrict__ msorted, const unsigned short* __restrict__ Wij,
    const unsigned short* __restrict__ h2, const int* __restrict__ rowEnd,
    float* __restrict__ agg)
{
    __shared__ unsigned short wlds[64 * 128];  // [p][c] bf16, stride 256B, swz ((p&7)<<4)
    __shared__ unsigned short xbuf[128 * 64];  // [c][p] bf16, stride 128B, swz ((c&7)<<4)
    __shared__ int           jjs[2][PB];
    __shared__ unsigned char rrs[2][PB];

    const int tid = threadIdx.x;
    const int w   = tid >> 6;
    const int l   = tid & 63;
    const int l15 = l & 15;
    const int l4  = l >> 4;
    const int swz = (l15 & 7) << 4;

    const int row0 = blockIdx.x * ROWS;
    const int s0 = (row0 == 0) ? 0 : rowEnd[row0 - 1];
    const int s1 = rowEnd[row0 + ROWS - 1];

    float4v accD[2];
    accD[0] = float4v{0.f, 0.f, 0.f, 0.f};
    accD[1] = float4v{0.f, 0.f, 0.f, 0.f};

    int tb = 0;
    for (int s = s0; s < s1; s += PB, tb ^= 1) {
        // ---- stage metadata ----
        if (tid < PB) {
            const int q  = s + tid;
            const int qc = q < s1 ? q : s1 - 1;
            const int4 m = msorted[qc];
            jjs[tb][tid] = m.y;
            rrs[tb][tid] = (q < s1) ? (unsigned char)m.z : (unsigned char)255;
        }
        // ---- stage Wij chunk: 4 threads per pair, 64B each ----
        {
            const int p4 = tid >> 2, q4 = tid & 3;
            const int q  = s + p4;
            const int qc = q < s1 ? q : s1 - 1;
            const int pid = msorted[qc].x;
            const char* src = (const char*)(Wij + (size_t)pid * 128) + q4 * 64;
            #pragma unroll
            for (int i = 0; i < 4; ++i) {
                const uint4 v = *(const uint4*)(src + i * 16);
                const int byte = p4 * 256 + ((q4 * 64 + i * 16) ^ ((p4 & 7) << 4));
                *(uint4*)((char*)wlds + byte) = v;
            }
        }
        __syncthreads();   // bar1: wlds + meta ready

        // ---- X build: X[p][c] = h2[jj][c] * Wij[p][c] -> bf16 [c][p] ----
        #pragma unroll
        for (int nt = 0; nt < 4; ++nt) {
            const int p   = nt * 16 + l15;
            const int jj  = jjs[tb][p] << 7;
            const int psw = (p & 7) << 4;
            #pragma unroll
            for (int mt = 0; mt < 2; ++mt) {
                const int c0 = w * 32 + mt * 16 + l4 * 4;
                const unsigned long long wv = *(const unsigned long long*)
                    ((const char*)wlds + p * 256 + ((c0 * 2) ^ psw));
                const unsigned long long hv = *(const unsigned long long*)&h2[jj + c0];
                #pragma unroll
                for (int j = 0; j < 4; ++j) {
                    const float wf = __uint_as_float((unsigned)((wv >> (16 * j)) & 0xFFFFULL) << 16);
                    const float hf = __uint_as_float((unsigned)((hv >> (16 * j)) & 0xFFFFULL) << 16);
                    const int c = c0 + j;
                    const int byte = c * 128 + ((p * 2) ^ ((c & 7) << 4));
                    *(unsigned short*)((char*)xbuf + byte) = bfs(hf * wf);
                }
            }
        }
        __syncthreads();   // bar2: xbuf ready

        // ---- AGG: aggT += X^T x S^T ----
        #pragma unroll
        for (int ks = 0; ks < 2; ++ks) {
            short8v sfr;
            #pragma unroll
            for (int e = 0; e < 8; ++e) {
                const int pr = ks * 32 + l4 * 8 + e;
                sfr[e] = (rrs[tb][pr] == (unsigned char)l15) ? (short)0x3F80 : (short)0;
            }
            #pragma unroll
            for (int mt = 0; mt < 2; ++mt) {
                const int c = w * 32 + mt * 16 + l15;
                const int byte = c * 128 + ((ks * 64 + l4 * 16) ^ swz);
                const short8v xfr = *(const short8v*)((const char*)xbuf + byte);
                accD[mt] = __builtin_amdgcn_mfma_f32_16x16x32_bf16(xfr, sfr, accD[mt], 0, 0, 0);
            }
        }
    }

    if (l15 < ROWS) {
        #pragma unroll
        for (int mt = 0; mt < 2; ++mt) {
            float4 v;
            v.x = accD[mt][0]; v.y = accD[mt][1]; v.z = accD[mt][2]; v.w = accD[mt][3];
            *(float4*)&agg[(size_t)(row0 + l15) * 128 + w * 32 + mt * 16 + l4 * 4] = v;
        }
    }
}

// ---------------------------------------------------------------------------
// FUSED fallback (round-6 kernel, used when ws_size is too small for split).
__global__ __launch_bounds__(256) void pairs_mfma_agg(
    const float* __restrict__ f_ij, const int* __restrict__ idx_i,
    const int* __restrict__ idx_j, const float* __restrict__ rcut,
    const float* __restrict__ Wf1, const float* __restrict__ bf1,
    const float* __restrict__ Wf2, const float* __restrict__ bf2,
    const unsigned short* __restrict__ h2, const int* __restrict__ rowEnd,
    const int* __restrict__ perm, float* __restrict__ agg)
{
    __shared__ unsigned short xt[64 * 128];
    __shared__ int   rrs[PB];
    __shared__ int   jjs[PB];
    __shared__ float rcs[PB];

    const int tid = threadIdx.x;
    const int w   = tid >> 6;
    const int l   = tid & 63;
    const int l15 = l & 15;
    const int l4  = l >> 4;
    const int swz = (l15 & 7) << 4;

    const int row0 = blockIdx.x * ROWS;
    const int s0 = (row0 == 0) ? 0 : rowEnd[row0 - 1];
    const int s1 = rowEnd[row0 + ROWS - 1];

    short8v wf1a[2];
    #pragma unroll
    for (int kt2 = 0; kt2 < 2; ++kt2) {
        const int ck = w * 32 + kt2 * 16 + l15;
        #pragma unroll
        for (int e = 0; e < 8; ++e) {
            const int r = l4 * 8 + e;
            const float val = (r < RDIM) ? Wf1[r * 128 + ck] : 0.0f;
            wf1a[kt2][e] = (short)bfs(val);
        }
    }
    short8v wf2a[2][4];
    #pragma unroll
    for (int mt = 0; mt < 2; ++mt) {
        const int c = w * 32 + mt * 16 + l15;
        #pragma unroll
        for (int ks = 0; ks < 4; ++ks) {
            #pragma unroll
            for (int e = 0; e < 8; ++e) {
                const int k = ks * 32 + l4 * 8 + e;
                wf2a[mt][ks][e] = (short)bfs(Wf2[k * 128 + c]);
            }
        }
    }
    float b1v[2][4], b2v[2][4];
    #pragma unroll
    for (int t = 0; t < 2; ++t)
        #pragma unroll
        for (int j = 0; j < 4; ++j) {
            b1v[t][j] = bf1[w * 32 + t * 16 + l4 * 4 + j];
            b2v[t][j] = bf2[w * 32 + t * 16 + l4 * 4 + j];
        }

    float4v accD[2];
    accD[0] = float4v{0.f, 0.f, 0.f, 0.f};
    accD[1] = float4v{0.f, 0.f, 0.f, 0.f};

    for (int s = s0; s < s1; s += PB) {
        __syncthreads();

        if (tid < PB) {
            const int q  = s + tid;
            const int qc = q < s1 ? q : s1 - 1;
            const int pid = perm[qc];
            rrs[tid] = idx_i[pid] - row0;
            jjs[tid] = idx_j[pid];
            rcs[tid] = (q < s1) ? rcut[pid] : 0.0f;
        }

        short8v ffr[4];
        #pragma unroll
        for (int nt = 0; nt < 4; ++nt) {
            const int q = s + nt * 16 + l15;
            const int pid = perm[q < s1 ? q : s1 - 1];
            const float* fb = &f_ij[(size_t)pid * RDIM];
            float4 fa = {0.f, 0.f, 0.f, 0.f}, fc = {0.f, 0.f, 0.f, 0.f};
            if (l4 < 3) fa = *(const float4*)(fb + l4 * 8);
            if (l4 < 2) fc = *(const float4*)(fb + l4 * 8 + 4);
            union { unsigned u[4]; short8v v; } pk;
            pk.u[0] = pkbf(fa.x, fa.y); pk.u[1] = pkbf(fa.z, fa.w);
            pk.u[2] = pkbf(fc.x, fc.y); pk.u[3] = pkbf(fc.z, fc.w);
            ffr[nt] = pk.v;
        }
        __syncthreads();

        unsigned long long hvb[4][2];
        #pragma unroll
        for (int nt = 0; nt < 4; ++nt) {
            const int gj = jjs[nt * 16 + l15] << 7;
            hvb[nt][0] = *(const unsigned long long*)&h2[gj + w * 32 + l4 * 4];
            hvb[nt][1] = *(const unsigned long long*)&h2[gj + w * 32 + 16 + l4 * 4];
        }

        #pragma unroll
        for (int kt2 = 0; kt2 < 2; ++kt2) {
            #pragma unroll
            for (int nt = 0; nt < 4; ++nt) {
                float4v acc1 = {0.f, 0.f, 0.f, 0.f};
                acc1 = __builtin_amdgcn_mfma_f32_16x16x32_bf16(wf1a[kt2], ffr[nt], acc1, 0, 0, 0);
                const unsigned lo = pkbf(sspf_fast(acc1[0] + b1v[kt2][0]),
                                         sspf_fast(acc1[1] + b1v[kt2][1]));
                const unsigned hi = pkbf(sspf_fast(acc1[2] + b1v[kt2][2]),
                                         sspf_fast(acc1[3] + b1v[kt2][3]));
                const int row = nt * 16 + l15;
                const int byte = row * 256 + ((w * 64 + kt2 * 32 + l4 * 8) ^ swz);
                *(unsigned long long*)((char*)xt + byte) =
                    (unsigned long long)lo | ((unsigned long long)hi << 32);
            }
        }
        __syncthreads();

        float4v a2[2][4];
        #pragma unroll
        for (int mt = 0; mt < 2; ++mt)
            #pragma unroll
            for (int nt = 0; nt < 4; ++nt)
                a2[mt][nt] = float4v{0.f, 0.f, 0.f, 0.f};

        #pragma unroll
        for (int ks = 0; ks < 4; ++ks) {
            short8v bfr[4];
            #pragma unroll
            for (int nt = 0; nt < 4; ++nt) {
                const int row = nt * 16 + l15;
                const int byte = row * 256 + ((ks * 64 + l4 * 16) ^ swz);
                bfr[nt] = *(const short8v*)((const char*)xt + byte);
            }
            #pragma unroll
            for (int mt = 0; mt < 2; ++mt)
                #pragma unroll
                for (int nt = 0; nt < 4; ++nt)
                    a2[mt][nt] = __builtin_amdgcn_mfma_f32_16x16x32_bf16(
                        wf2a[mt][ks], bfr[nt], a2[mt][nt], 0, 0, 0);
        }
        __syncthreads();

        #pragma unroll
        for (int nt = 0; nt < 4; ++nt) {
            const int p = nt * 16 + l15;
            const float r = rcs[p];
            #pragma unroll
            for (int mt = 0; mt < 2; ++mt) {
                #pragma unroll
                for (int j = 0; j < 4; ++j) {
                    const int c = w * 32 + mt * 16 + l4 * 4 + j;
                    const float hf = __uint_as_float(
                        (unsigned)((hvb[nt][mt] >> (16 * j)) & 0xFFFFULL) << 16);
                    const float xv = hf * ((a2[mt][nt][j] + b2v[mt][j]) * r);
                    const int byte = c * 128 + ((p * 2) ^ ((c & 7) << 4));
                    *(unsigned short*)((char*)xt + byte) = bfs(xv);
                }
            }
        }
        __syncthreads();

        #pragma unroll
        for (int ks = 0; ks < 2; ++ks) {
            short8v sfr;
            #pragma unroll
            for (int e = 0; e < 8; ++e) {
                const int pr = ks * 32 + l4 * 8 + e;
                sfr[e] = (rrs[pr] == l15) ? (short)0x3F80 : (short)0;
            }
            #pragma unroll
            for (int mt = 0; mt < 2; ++mt) {
                const int c = w * 32 + mt * 16 + l15;
                const int byte = c * 128 + ((ks * 64 + l4 * 16) ^ swz);
                const short8v xfr = *(const short8v*)((const char*)xt + byte);
                accD[mt] = __builtin_amdgcn_mfma_f32_16x16x32_bf16(xfr, sfr, accD[mt], 0, 0, 0);
            }
        }
    }

    if (l15 < ROWS) {
        #pragma unroll
        for (int mt = 0; mt < 2; ++mt) {
            float4 v;
            v.x = accD[mt][0]; v.y = accD[mt][1]; v.z = accD[mt][2]; v.w = accD[mt][3];
            *(float4*)&agg[(size_t)(row0 + l15) * 128 + w * 32 + mt * 16 + l4 * 4] = v;
        }
    }
}

extern "C" void kernel_launch(void* const* d_in, const int* in_sizes, int n_in,
                              void* d_out, int out_size, void* d_ws, size_t ws_size,
                              hipStream_t stream) {
    const float* x     = (const float*)d_in[0];
    const float* f_ij  = (const float*)d_in[1];
    const int*   idx_i = (const int*)  d_in[2];
    const int*   idx_j = (const int*)  d_in[3];
    const float* rcut  = (const float*)d_in[4];
    const float* W_in  = (const float*)d_in[5];
    const float* b_in  = (const float*)d_in[6];
    const float* Wf1   = (const float*)d_in[7];
    const float* bf1   = (const float*)d_in[8];
    const float* Wf2   = (const float*)d_in[9];
    const float* bf2   = (const float*)d_in[10];
    const float* Wo1   = (const float*)d_in[11];
    const float* bo1   = (const float*)d_in[12];
    const float* Wo2   = (const float*)d_in[13];
    const float* bo2   = (const float*)d_in[14];
    float* out = (float*)d_out;

    // common ws layout:
    //   h2      : bf16 [8000][128]                      2,048,000 B
    //   agg     : f32  [8000][128]                      4,096,000 B
    //   t1      : f32  [8000][128] (perm/cnt overlay)   4,096,000 B
    // split-only extra:
    //   msorted : int4 [512000]                         8,192,000 B
    //   Wij     : bf16 [512000][128]                  131,072,000 B
    unsigned short* h2 = (unsigned short*)d_ws;
    float* agg = (float*)((char*)d_ws + 2048000);
    float* t1  = (float*)((char*)d_ws + 2048000 + 4096000);
    int* perm   = (int*)t1;
    int* cnt    = (int*)((char*)t1 + (size_t)NPAIR * 4);
    int* cursor = cnt + 8001;
    int4* msorted      = (int4*)((char*)d_ws + 10240000);
    unsigned short* Wij = (unsigned short*)((char*)d_ws + 10240000 + 8192000);
    const size_t SPLIT_BYTES = 10240000ull + 8192000ull + 131072000ull;

    const bool use_split = (ws_size >= SPLIT_BYTES);

    // CSR sort of pairs by idx_i
    hipMemsetAsync(cnt, 0, (BN + 1) * sizeof(int), stream);
    hist_kernel<<<NPAIR / 256, 256, 0, stream>>>(idx_i, cnt);
    scan_kernel<<<1, 1024, 0, stream>>>(cnt, cursor);
    if (use_split) {
        scatter_split<<<NPAIR / 256, 256, 0, stream>>>(idx_i, idx_j, cursor, msorted);
    } else {
        scatter_kernel<<<NPAIR / 256, 256, 0, stream>>>(idx_i, cursor, perm);
    }

    // h2 = bf16(x @ W_in + b_in)
    rowgemm_kernel<false, true><<<BN / 16, 256, 0, stream>>>(x, W_in, b_in, h2);

    if (use_split) {
        filter_gemm<<<NBLK_FILTER, 256, 0, stream>>>(
            f_ij, rcut, Wf1, bf1, Wf2, bf2, Wij);
        pairs_agg<<<BN / ROWS, 256, 0, stream>>>(
            msorted, Wij, h2, cursor, agg);
    } else {
        pairs_mfma_agg<<<BN / ROWS, 256, 0, stream>>>(
            f_ij, idx_i, idx_j, rcut, Wf1, bf1, Wf2, bf2, h2, cursor, perm, agg);
    }

    // out = ssp(agg @ Wo1 + bo1) @ Wo2 + bo2
    rowgemm_kernel<true,  false><<<BN / 16, 256, 0, stream>>>(agg, Wo1, bo1, t1);
    rowgemm_kernel<false, false><<<BN / 16, 256, 0, stream>>>(t1, Wo2, bo2, out);
}

// Round 10
// 240.251 us; speedup vs baseline: 1.2742x; 1.0138x over previous
//
#include <hip/hip_runtime.h>
#include <hip/hip_bf16.h>
#include <math.h>

#define FDIM 128
#define RDIM 20
#define BN   8000
#define NPAIR 512000
#define PB   64
#define ROWS 8
#define NCHUNK (NPAIR / PB)
#define FILTER_GRID 2048

typedef __attribute__((ext_vector_type(8))) short short8v;
typedef __attribute__((ext_vector_type(4))) float float4v;

// fast ShiftedSoftplus: max(x,0) + log(1+exp(-|x|)) - ln2, fast intrinsics
__device__ __forceinline__ float sspf_fast(float x) {
    return fmaxf(x, 0.0f) + __logf(1.0f + __expf(-fabsf(x))) - 0.69314718055994531f;
}
// precise version for the small row-GEMMs (cheap there)
__device__ __forceinline__ float sspf(float x) {
    return fmaxf(x, 0.0f) + log1pf(expf(-fabsf(x))) - 0.69314718055994531f;
}

// HW bf16 converts (v_cvt_pk_bf16_f32), RNE
__device__ __forceinline__ unsigned short bfs(float a) {
    union { __hip_bfloat16 h; unsigned short u; } v;
    v.h = __float2bfloat16(a);
    return v.u;
}
__device__ __forceinline__ unsigned pkbf(float a, float b) {
    union { __hip_bfloat162 h; unsigned u; } v;
    v.h = __float22bfloat162_rn(make_float2(a, b));
    return v.u;
}

// ---------------------------------------------------------------------------
// CSR preprocessing: histogram -> exclusive scan -> scatter
__global__ __launch_bounds__(256) void hist_kernel(
    const int* __restrict__ idx_i, int* __restrict__ cnt)
{
    const int p = blockIdx.x * 256 + threadIdx.x;
    if (p < NPAIR) atomicAdd(&cnt[idx_i[p]], 1);
}

__global__ __launch_bounds__(1024) void scan_kernel(
    const int* __restrict__ cnt, int* __restrict__ cursor)
{
    __shared__ int part[1024];
    const int t = threadIdx.x;
    int v[8]; int sum = 0;
    #pragma unroll
    for (int k = 0; k < 8; ++k) {
        const int i = t * 8 + k;
        const int c = (i < BN) ? cnt[i] : 0;
        v[k] = sum; sum += c;
    }
    part[t] = sum;
    __syncthreads();
    for (int off = 1; off < 1024; off <<= 1) {
        const int x = (t >= off) ? part[t - off] : 0;
        __syncthreads();
        part[t] += x;
        __syncthreads();
    }
    const int base = (t == 0) ? 0 : part[t - 1];
    #pragma unroll
    for (int k = 0; k < 8; ++k) {
        const int i = t * 8 + k;
        if (i < BN) cursor[i] = base + v[k];
    }
}

// fused-fallback path: perm only
__global__ __launch_bounds__(256) void scatter_kernel(
    const int* __restrict__ idx_i, int* __restrict__ cursor, int* __restrict__ perm)
{
    const int p = blockIdx.x * 256 + threadIdx.x;
    if (p < NPAIR) {
        const int pos = atomicAdd(&cursor[idx_i[p]], 1);
        perm[pos] = p;
    }
}

// split path: materialize sorted f (bf16, 64B/pair) + meta {jj, ii, rc}
__global__ __launch_bounds__(256) void scatter_sorted(
    const int* __restrict__ idx_i, const int* __restrict__ idx_j,
    const float* __restrict__ rcut, const float* __restrict__ f_ij,
    int* __restrict__ cursor, int4* __restrict__ meta,
    unsigned short* __restrict__ fsorted)
{
    const int p = blockIdx.x * 256 + threadIdx.x;
    if (p >= NPAIR) return;
    const int ii = idx_i[p];
    const int pos = atomicAdd(&cursor[ii], 1);
    meta[pos] = make_int4(idx_j[p], ii, __float_as_int(rcut[p]), 0);

    const float4* fb = (const float4*)(f_ij + (size_t)p * RDIM);  // 80B, 16B-aligned
    const float4 f0 = fb[0], f1 = fb[1], f2 = fb[2], f3 = fb[3], f4 = fb[4];
    uint4 d0, d1, d2, d3;
    d0.x = pkbf(f0.x, f0.y); d0.y = pkbf(f0.z, f0.w);
    d0.z = pkbf(f1.x, f1.y); d0.w = pkbf(f1.z, f1.w);
    d1.x = pkbf(f2.x, f2.y); d1.y = pkbf(f2.z, f2.w);
    d1.z = pkbf(f3.x, f3.y); d1.w = pkbf(f3.z, f3.w);
    d2.x = pkbf(f4.x, f4.y); d2.y = pkbf(f4.z, f4.w);
    d2.z = 0; d2.w = 0;
    d3.x = 0; d3.y = 0; d3.z = 0; d3.w = 0;
    uint4* dst = (uint4*)(fsorted + (size_t)pos * 32);
    dst[0] = d0; dst[1] = d1; dst[2] = d2; dst[3] = d3;
}

// ---------------------------------------------------------------------------
// C[p, :] = act(A[p, :] @ W + bias), 16 rows per block, 256 threads.
template<bool SSP, bool BF16OUT>
__global__ __launch_bounds__(256) void rowgemm_kernel(
    const float* __restrict__ A, const float* __restrict__ W,
    const float* __restrict__ bias, void* __restrict__ Cv)
{
    __shared__ float rowlds[16 * 128];
    const int tid = threadIdx.x;
    const int blk = blockIdx.x;
    for (int s = tid; s < 16 * 128; s += 256)
        rowlds[s] = A[blk * 16 * 128 + s];
    __syncthreads();

    const int lane = tid & 63;
    const int wave = tid >> 6;
    const float b0 = bias[lane];
    const float b1 = bias[64 + lane];
    float acc[4][2];
    #pragma unroll
    for (int rr = 0; rr < 4; ++rr) { acc[rr][0] = b0; acc[rr][1] = b1; }

    #pragma unroll 4
    for (int m = 0; m < 128; ++m) {
        const float w0 = W[m * 128 + lane];
        const float w1 = W[m * 128 + 64 + lane];
        #pragma unroll
        for (int rr = 0; rr < 4; ++rr) {
            const float av = rowlds[(wave * 4 + rr) * 128 + m];
            acc[rr][0] = fmaf(av, w0, acc[rr][0]);
            acc[rr][1] = fmaf(av, w1, acc[rr][1]);
        }
    }

    #pragma unroll
    for (int rr = 0; rr < 4; ++rr) {
        const int p = blk * 16 + wave * 4 + rr;
        float v0 = acc[rr][0], v1 = acc[rr][1];
        if (SSP) { v0 = sspf(v0); v1 = sspf(v1); }
        if (BF16OUT) {
            unsigned short* C = (unsigned short*)Cv;
            C[p * 128 + lane]      = bfs(v0);
            C[p * 128 + 64 + lane] = bfs(v1);
        } else {
            float* C = (float*)Cv;
            C[p * 128 + lane]      = v0;
            C[p * 128 + 64 + lane] = v1;
        }
    }
}

// ---------------------------------------------------------------------------
// SPLIT kernel A: filter net over SORTED pairs, all-sequential streams.
// Writes X^T[chunk][c=128][p=64] bf16 where X[p][c] = h2[jj_p][c]*Wij[p][c].
__global__ __launch_bounds__(256) void filter_sorted(
    const unsigned short* __restrict__ fsorted, const int4* __restrict__ meta,
    const unsigned short* __restrict__ h2,
    const float* __restrict__ Wf1, const float* __restrict__ bf1,
    const float* __restrict__ Wf2, const float* __restrict__ bf2,
    unsigned short* __restrict__ Xt)
{
    __shared__ unsigned short act[64 * 128];      // [p][k] bf16, stride 256B, swz ((p&7)<<4)
    __shared__ unsigned short xpose[4][32 * 64];  // per-wave [c'][p], swz ((c'&7)<<4)
    const int tid = threadIdx.x;
    const int w   = tid >> 6;
    const int l   = tid & 63;
    const int l15 = l & 15;
    const int l4  = l >> 4;
    const int swz = (l15 & 7) << 4;

    // ---- weight fragments in registers (once per block) ----
    short8v wf1a[2];
    #pragma unroll
    for (int kt2 = 0; kt2 < 2; ++kt2) {
        const int ck = w * 32 + kt2 * 16 + l15;
        #pragma unroll
        for (int e = 0; e < 8; ++e) {
            const int r = l4 * 8 + e;
            const float val = (r < RDIM) ? Wf1[r * 128 + ck] : 0.0f;
            wf1a[kt2][e] = (short)bfs(val);
        }
    }
    short8v wf2a[2][4];
    #pragma unroll
    for (int mt = 0; mt < 2; ++mt) {
        const int c = w * 32 + mt * 16 + l15;
        #pragma unroll
        for (int ks = 0; ks < 4; ++ks) {
            #pragma unroll
            for (int e = 0; e < 8; ++e) {
                const int k = ks * 32 + l4 * 8 + e;
                wf2a[mt][ks][e] = (short)bfs(Wf2[k * 128 + c]);
            }
        }
    }
    float b1v[2][4], b2v[2][4];
    #pragma unroll
    for (int t = 0; t < 2; ++t)
        #pragma unroll
        for (int j = 0; j < 4; ++j) {
            b1v[t][j] = bf1[w * 32 + t * 16 + l4 * 4 + j];
            b2v[t][j] = bf2[w * 32 + t * 16 + l4 * 4 + j];
        }

    for (int chunk = blockIdx.x; chunk < NCHUNK; chunk += FILTER_GRID) {
        const int pbase = chunk * PB;

        // ---- sequential loads: f-frags + per-pair meta (regs, no LDS) ----
        short8v ffr[4];
        float rc[4];
        int jj[4];
        #pragma unroll
        for (int nt = 0; nt < 4; ++nt) {
            const int q = pbase + nt * 16 + l15;
            const uint4* fr = (const uint4*)(fsorted + (size_t)q * 32);
            union { uint4 u; short8v v; } cv;
            cv.u = fr[l4];
            ffr[nt] = cv.v;
            const int4 m = meta[q];
            jj[nt] = m.x;
            rc[nt] = __int_as_float(m.z);
        }

        __syncthreads();   // prev chunk's L2 readers done with act

        // ---- layer 1 -> act ----
        #pragma unroll
        for (int kt2 = 0; kt2 < 2; ++kt2) {
            #pragma unroll
            for (int nt = 0; nt < 4; ++nt) {
                float4v acc1 = {0.f, 0.f, 0.f, 0.f};
                acc1 = __builtin_amdgcn_mfma_f32_16x16x32_bf16(wf1a[kt2], ffr[nt], acc1, 0, 0, 0);
                const unsigned lo = pkbf(sspf_fast(acc1[0] + b1v[kt2][0]),
                                         sspf_fast(acc1[1] + b1v[kt2][1]));
                const unsigned hi = pkbf(sspf_fast(acc1[2] + b1v[kt2][2]),
                                         sspf_fast(acc1[3] + b1v[kt2][3]));
                const int row = nt * 16 + l15;
                const int byte = row * 256 + ((w * 64 + kt2 * 32 + l4 * 8) ^ swz);
                *(unsigned long long*)((char*)act + byte) =
                    (unsigned long long)lo | ((unsigned long long)hi << 32);
            }
        }
        __syncthreads();   // act ready (cross-wave)

        // ---- layer 2 (both halves) ----
        float4v a2[2][4];
        #pragma unroll
        for (int mt = 0; mt < 2; ++mt)
            #pragma unroll
            for (int nt = 0; nt < 4; ++nt)
                a2[mt][nt] = float4v{0.f, 0.f, 0.f, 0.f};

        #pragma unroll
        for (int ks = 0; ks < 4; ++ks) {
            short8v bfr[4];
            #pragma unroll
            for (int nt = 0; nt < 4; ++nt) {
                const int row = nt * 16 + l15;
                const int byte = row * 256 + ((ks * 64 + l4 * 16) ^ swz);
                bfr[nt] = *(const short8v*)((const char*)act + byte);
            }
            #pragma unroll
            for (int mt = 0; mt < 2; ++mt)
                #pragma unroll
                for (int nt = 0; nt < 4; ++nt)
                    a2[mt][nt] = __builtin_amdgcn_mfma_f32_16x16x32_bf16(
                        wf2a[mt][ks], bfr[nt], a2[mt][nt], 0, 0, 0);
        }

        // ---- h gather (L2-resident) + X build into wave-local xpose ----
        unsigned short* xp = &xpose[w][0];
        #pragma unroll
        for (int nt = 0; nt < 4; ++nt) {
            const int gj = jj[nt] << 7;
            const int p  = nt * 16 + l15;
            #pragma unroll
            for (int mt = 0; mt < 2; ++mt) {
                const unsigned long long hv =
                    *(const unsigned long long*)&h2[gj + w * 32 + mt * 16 + l4 * 4];
                #pragma unroll
                for (int j = 0; j < 4; ++j) {
                    const float hf = __uint_as_float(
                        (unsigned)((hv >> (16 * j)) & 0xFFFFULL) << 16);
                    const int cp = mt * 16 + l4 * 4 + j;   // c - w*32
                    const float xv = hf * ((a2[mt][nt][j] + b2v[mt][j]) * rc[nt]);
                    const int byte = cp * 128 + ((p * 2) ^ ((cp & 7) << 4));
                    *(unsigned short*)((char*)xp + byte) = bfs(xv);
                }
            }
        }

        // ---- wave-local coalesced writeback of X^T (no barrier needed) ----
        char* dst = (char*)Xt + (size_t)chunk * 16384;
        #pragma unroll
        for (int i = 0; i < 4; ++i) {
            const int r  = i * 8 + (l >> 3);
            const int lb = r * 128 + ((((l & 7) * 16)) ^ ((r & 7) << 4));
            const uint4 v = *(const uint4*)((const char*)xp + lb);
            *(uint4*)(dst + (w * 32 + r) * 128 + (l & 7) * 16) = v;
        }
    }
}

// ---------------------------------------------------------------------------
// SPLIT kernel B: pure-stream aggregation. Block b owns rows [b*8, b*8+8).
// Reads X^T chunks sequentially, gates by ii, accumulates in MFMA D regs.
__global__ __launch_bounds__(256) void agg_stream(
    const int4* __restrict__ meta, const unsigned short* __restrict__ Xt,
    const int* __restrict__ rowEnd, float* __restrict__ agg)
{
    __shared__ int rrsF[2][PB];
    const int tid = threadIdx.x;
    const int w   = tid >> 6;
    const int l   = tid & 63;
    const int l15 = l & 15;
    const int l4  = l >> 4;

    const int row0 = blockIdx.x * ROWS;
    const int s0 = (row0 == 0) ? 0 : rowEnd[row0 - 1];
    const int s1 = rowEnd[row0 + ROWS - 1];
    const int ch0 = s0 >> 6;
    const int ch1 = (s1 + PB - 1) >> 6;

    float4v accD[2];
    accD[0] = float4v{0.f, 0.f, 0.f, 0.f};
    accD[1] = float4v{0.f, 0.f, 0.f, 0.f};

    int tb = 0;
    for (int ch = ch0; ch < ch1; ++ch, tb ^= 1) {
        if (tid < PB) {
            const int q = ch * PB + tid;
            rrsF[tb][tid] = (q < NPAIR) ? (meta[q].y - row0) : -1;
        }
        __syncthreads();

        const char* base = (const char*)Xt + (size_t)ch * 16384;
        #pragma unroll
        for (int ks = 0; ks < 2; ++ks) {
            short8v sfr;
            #pragma unroll
            for (int e = 0; e < 8; ++e) {
                const int pr = ks * 32 + l4 * 8 + e;
                sfr[e] = (rrsF[tb][pr] == l15) ? (short)0x3F80 : (short)0;
            }
            #pragma unroll
            for (int mt = 0; mt < 2; ++mt) {
                const short8v xfr = *(const short8v*)
                    (base + (w * 32 + mt * 16 + l15) * 128 + ks * 64 + l4 * 16);
                accD[mt] = __builtin_amdgcn_mfma_f32_16x16x32_bf16(xfr, sfr, accD[mt], 0, 0, 0);
            }
        }
    }

    if (l15 < ROWS) {
        #pragma unroll
        for (int mt = 0; mt < 2; ++mt) {
            float4 v;
            v.x = accD[mt][0]; v.y = accD[mt][1]; v.z = accD[mt][2]; v.w = accD[mt][3];
            *(float4*)&agg[(size_t)(row0 + l15) * 128 + w * 32 + mt * 16 + l4 * 4] = v;
        }
    }
}

// ---------------------------------------------------------------------------
// FUSED fallback (round-6 kernel, used when ws_size is too small for split).
__global__ __launch_bounds__(256) void pairs_mfma_agg(
    const float* __restrict__ f_ij, const int* __restrict__ idx_i,
    const int* __restrict__ idx_j, const float* __restrict__ rcut,
    const float* __restrict__ Wf1, const float* __restrict__ bf1,
    const float* __restrict__ Wf2, const float* __restrict__ bf2,
    const unsigned short* __restrict__ h2, const int* __restrict__ rowEnd,
    const int* __restrict__ perm, float* __restrict__ agg)
{
    __shared__ unsigned short xt[64 * 128];
    __shared__ int   rrs[PB];
    __shared__ int   jjs[PB];
    __shared__ float rcs[PB];

    const int tid = threadIdx.x;
    const int w   = tid >> 6;
    const int l   = tid & 63;
    const int l15 = l & 15;
    const int l4  = l >> 4;
    const int swz = (l15 & 7) << 4;

    const int row0 = blockIdx.x * ROWS;
    const int s0 = (row0 == 0) ? 0 : rowEnd[row0 - 1];
    const int s1 = rowEnd[row0 + ROWS - 1];

    short8v wf1a[2];
    #pragma unroll
    for (int kt2 = 0; kt2 < 2; ++kt2) {
        const int ck = w * 32 + kt2 * 16 + l15;
        #pragma unroll
        for (int e = 0; e < 8; ++e) {
            const int r = l4 * 8 + e;
            const float val = (r < RDIM) ? Wf1[r * 128 + ck] : 0.0f;
            wf1a[kt2][e] = (short)bfs(val);
        }
    }
    short8v wf2a[2][4];
    #pragma unroll
    for (int mt = 0; mt < 2; ++mt) {
        const int c = w * 32 + mt * 16 + l15;
        #pragma unroll
        for (int ks = 0; ks < 4; ++ks) {
            #pragma unroll
            for (int e = 0; e < 8; ++e) {
                const int k = ks * 32 + l4 * 8 + e;
                wf2a[mt][ks][e] = (short)bfs(Wf2[k * 128 + c]);
            }
        }
    }
    float b1v[2][4], b2v[2][4];
    #pragma unroll
    for (int t = 0; t < 2; ++t)
        #pragma unroll
        for (int j = 0; j < 4; ++j) {
            b1v[t][j] = bf1[w * 32 + t * 16 + l4 * 4 + j];
            b2v[t][j] = bf2[w * 32 + t * 16 + l4 * 4 + j];
        }

    float4v accD[2];
    accD[0] = float4v{0.f, 0.f, 0.f, 0.f};
    accD[1] = float4v{0.f, 0.f, 0.f, 0.f};

    for (int s = s0; s < s1; s += PB) {
        __syncthreads();

        if (tid < PB) {
            const int q  = s + tid;
            const int qc = q < s1 ? q : s1 - 1;
            const int pid = perm[qc];
            rrs[tid] = idx_i[pid] - row0;
            jjs[tid] = idx_j[pid];
            rcs[tid] = (q < s1) ? rcut[pid] : 0.0f;
        }

        short8v ffr[4];
        #pragma unroll
        for (int nt = 0; nt < 4; ++nt) {
            const int q = s + nt * 16 + l15;
            const int pid = perm[q < s1 ? q : s1 - 1];
            const float* fb = &f_ij[(size_t)pid * RDIM];
            float4 fa = {0.f, 0.f, 0.f, 0.f}, fc = {0.f, 0.f, 0.f, 0.f};
            if (l4 < 3) fa = *(const float4*)(fb + l4 * 8);
            if (l4 < 2) fc = *(const float4*)(fb + l4 * 8 + 4);
            union { unsigned u[4]; short8v v; } pk;
            pk.u[0] = pkbf(fa.x, fa.y); pk.u[1] = pkbf(fa.z, fa.w);
            pk.u[2] = pkbf(fc.x, fc.y); pk.u[3] = pkbf(fc.z, fc.w);
            ffr[nt] = pk.v;
        }
        __syncthreads();

        unsigned long long hvb[4][2];
        #pragma unroll
        for (int nt = 0; nt < 4; ++nt) {
            const int gj = jjs[nt * 16 + l15] << 7;
            hvb[nt][0] = *(const unsigned long long*)&h2[gj + w * 32 + l4 * 4];
            hvb[nt][1] = *(const unsigned long long*)&h2[gj + w * 32 + 16 + l4 * 4];
        }

        #pragma unroll
        for (int kt2 = 0; kt2 < 2; ++kt2) {
            #pragma unroll
            for (int nt = 0; nt < 4; ++nt) {
                float4v acc1 = {0.f, 0.f, 0.f, 0.f};
                acc1 = __builtin_amdgcn_mfma_f32_16x16x32_bf16(wf1a[kt2], ffr[nt], acc1, 0, 0, 0);
                const unsigned lo = pkbf(sspf_fast(acc1[0] + b1v[kt2][0]),
                                         sspf_fast(acc1[1] + b1v[kt2][1]));
                const unsigned hi = pkbf(sspf_fast(acc1[2] + b1v[kt2][2]),
                                         sspf_fast(acc1[3] + b1v[kt2][3]));
                const int row = nt * 16 + l15;
                const int byte = row * 256 + ((w * 64 + kt2 * 32 + l4 * 8) ^ swz);
                *(unsigned long long*)((char*)xt + byte) =
                    (unsigned long long)lo | ((unsigned long long)hi << 32);
            }
        }
        __syncthreads();

        float4v a2[2][4];
        #pragma unroll
        for (int mt = 0; mt < 2; ++mt)
            #pragma unroll
            for (int nt = 0; nt < 4; ++nt)
                a2[mt][nt] = float4v{0.f, 0.f, 0.f, 0.f};

        #pragma unroll
        for (int ks = 0; ks < 4; ++ks) {
            short8v bfr[4];
            #pragma unroll
            for (int nt = 0; nt < 4; ++nt) {
                const int row = nt * 16 + l15;
                const int byte = row * 256 + ((ks * 64 + l4 * 16) ^ swz);
                bfr[nt] = *(const short8v*)((const char*)xt + byte);
            }
            #pragma unroll
            for (int mt = 0; mt < 2; ++mt)
                #pragma unroll
                for (int nt = 0; nt < 4; ++nt)
                    a2[mt][nt] = __builtin_amdgcn_mfma_f32_16x16x32_bf16(
                        wf2a[mt][ks], bfr[nt], a2[mt][nt], 0, 0, 0);
        }
        __syncthreads();

        #pragma unroll
        for (int nt = 0; nt < 4; ++nt) {
            const int p = nt * 16 + l15;
            const float r = rcs[p];
            #pragma unroll
            for (int mt = 0; mt < 2; ++mt) {
                #pragma unroll
                for (int j = 0; j < 4; ++j) {
                    const int c = w * 32 + mt * 16 + l4 * 4 + j;
                    const float hf = __uint_as_float(
                        (unsigned)((hvb[nt][mt] >> (16 * j)) & 0xFFFFULL) << 16);
                    const float xv = hf * ((a2[mt][nt][j] + b2v[mt][j]) * r);
                    const int byte = c * 128 + ((p * 2) ^ ((c & 7) << 4));
                    *(unsigned short*)((char*)xt + byte) = bfs(xv);
                }
            }
        }
        __syncthreads();

        #pragma unroll
        for (int ks = 0; ks < 2; ++ks) {
            short8v sfr;
            #pragma unroll
            for (int e = 0; e < 8; ++e) {
                const int pr = ks * 32 + l4 * 8 + e;
                sfr[e] = (rrs[pr] == l15) ? (short)0x3F80 : (short)0;
            }
            #pragma unroll
            for (int mt = 0; mt < 2; ++mt) {
                const int c = w * 32 + mt * 16 + l15;
                const int byte = c * 128 + ((ks * 64 + l4 * 16) ^ swz);
                const short8v xfr = *(const short8v*)((const char*)xt + byte);
                accD[mt] = __builtin_amdgcn_mfma_f32_16x16x32_bf16(xfr, sfr, accD[mt], 0, 0, 0);
            }
        }
    }

    if (l15 < ROWS) {
        #pragma unroll
        for (int mt = 0; mt < 2; ++mt) {
            float4 v;
            v.x = accD[mt][0]; v.y = accD[mt][1]; v.z = accD[mt][2]; v.w = accD[mt][3];
            *(float4*)&agg[(size_t)(row0 + l15) * 128 + w * 32 + mt * 16 + l4 * 4] = v;
        }
    }
}

extern "C" void kernel_launch(void* const* d_in, const int* in_sizes, int n_in,
                              void* d_out, int out_size, void* d_ws, size_t ws_size,
                              hipStream_t stream) {
    const float* x     = (const float*)d_in[0];
    const float* f_ij  = (const float*)d_in[1];
    const int*   idx_i = (const int*)  d_in[2];
    const int*   idx_j = (const int*)  d_in[3];
    const float* rcut  = (const float*)d_in[4];
    const float* W_in  = (const float*)d_in[5];
    const float* b_in  = (const float*)d_in[6];
    const float* Wf1   = (const float*)d_in[7];
    const float* bf1   = (const float*)d_in[8];
    const float* Wf2   = (const float*)d_in[9];
    const float* bf2   = (const float*)d_in[10];
    const float* Wo1   = (const float*)d_in[11];
    const float* bo1   = (const float*)d_in[12];
    const float* Wo2   = (const float*)d_in[13];
    const float* bo2   = (const float*)d_in[14];
    float* out = (float*)d_out;

    // split layout:
    //   h2      bf16[8000][128]          @ 0            (2,048,000)
    //   agg     f32 [8000][128]          @ 2,048,000    (4,096,000)
    //   meta    int4[512000]             @ 6,144,000    (8,192,000)
    //   cnt     int [8001]               @ 14,336,000
    //   cursor  int [8000]               @ 14,368,004
    //   fsorted bf16[512000][32]         @ 14,400,512   (32,768,000)
    //   Xt      bf16[8000][128][64]      @ 47,168,512   (131,072,000)
    //   t1 aliases fsorted (dead after filter_sorted)
    unsigned short* h2 = (unsigned short*)d_ws;
    float* agg = (float*)((char*)d_ws + 2048000);
    int4* meta = (int4*)((char*)d_ws + 6144000);
    int* cnt    = (int*)((char*)d_ws + 14336000);
    int* cursor = cnt + 8001;
    unsigned short* fsorted = (unsigned short*)((char*)d_ws + 14400512);
    unsigned short* Xt      = (unsigned short*)((char*)d_ws + 47168512);
    float* t1_split = (float*)fsorted;
    const size_t SPLIT_BYTES = 47168512ull + 131072000ull;

    // fallback (r6/r9) layout: h2 @0, agg @2,048,000, t1 @6,144,000 (perm overlay)
    float* t1_fb = (float*)((char*)d_ws + 6144000);
    int* perm_fb   = (int*)t1_fb;
    int* cnt_fb    = (int*)((char*)t1_fb + (size_t)NPAIR * 4);
    int* cursor_fb = cnt_fb + 8001;

    const bool use_split = (ws_size >= SPLIT_BYTES);

    if (use_split) {
        hipMemsetAsync(cnt, 0, (BN + 1) * sizeof(int), stream);
        hist_kernel<<<NPAIR / 256, 256, 0, stream>>>(idx_i, cnt);
        scan_kernel<<<1, 1024, 0, stream>>>(cnt, cursor);
        scatter_sorted<<<NPAIR / 256, 256, 0, stream>>>(
            idx_i, idx_j, rcut, f_ij, cursor, meta, fsorted);

        rowgemm_kernel<false, true><<<BN / 16, 256, 0, stream>>>(x, W_in, b_in, h2);

        filter_sorted<<<FILTER_GRID, 256, 0, stream>>>(
            fsorted, meta, h2, Wf1, bf1, Wf2, bf2, Xt);
        agg_stream<<<BN / ROWS, 256, 0, stream>>>(meta, Xt, cursor, agg);

        rowgemm_kernel<true,  false><<<BN / 16, 256, 0, stream>>>(agg, Wo1, bo1, t1_split);
        rowgemm_kernel<false, false><<<BN / 16, 256, 0, stream>>>(t1_split, Wo2, bo2, out);
    } else {
        hipMemsetAsync(cnt_fb, 0, (BN + 1) * sizeof(int), stream);
        hist_kernel<<<NPAIR / 256, 256, 0, stream>>>(idx_i, cnt_fb);
        scan_kernel<<<1, 1024, 0, stream>>>(cnt_fb, cursor_fb);
        scatter_kernel<<<NPAIR / 256, 256, 0, stream>>>(idx_i, cursor_fb, perm_fb);

        rowgemm_kernel<false, true><<<BN / 16, 256, 0, stream>>>(x, W_in, b_in, h2);

        pairs_mfma_agg<<<BN / ROWS, 256, 0, stream>>>(
            f_ij, idx_i, idx_j, rcut, Wf1, bf1, Wf2, bf2, h2, cursor_fb, perm_fb, agg);

        rowgemm_kernel<true,  false><<<BN / 16, 256, 0, stream>>>(agg, Wo1, bo1, t1_fb);
        rowgemm_kernel<false, false><<<BN / 16, 256, 0, stream>>>(t1_fb, Wo2, bo2, out);
    }
}